// Round 10
// baseline (826.675 us; speedup 1.0000x reference)
//
#include <hip/hip_runtime.h>
#include <math.h>

#define T_ 80
#define B_ 32
#define N_ 2560            // T_*B_
#define LH_ 256

typedef __attribute__((ext_vector_type(8))) short short8;
typedef __attribute__((ext_vector_type(4))) float f32x4;
#define MFMA16(a, b, c) __builtin_amdgcn_mfma_f32_16x16x32_bf16((a), (b), (c), 0, 0, 0)

__device__ __forceinline__ float lrelu(float v) { return v > 0.f ? v : 0.01f * v; }
__device__ __forceinline__ short f2bf(float f) {        // RNE float->bf16 bits
    unsigned u = __float_as_uint(f);
    return (short)((u + 0x7fffu + ((u >> 16) & 1u)) >> 16);
}

// ========== fused weight-pack (one kernel) ======================================
__global__ void pack_all_k(const float* __restrict__ c1w, const float* __restrict__ c2w,
                           const float* __restrict__ c3w, const float* __restrict__ fcw,
                           const float* __restrict__ wih,
                           short* __restrict__ wp1, short* __restrict__ wp2,
                           short* __restrict__ wp3, short* __restrict__ wfcP,
                           short* __restrict__ wihP) {
    int blk = blockIdx.x, tidx = threadIdx.x;
    if (blk < 6272) {                                   // fc: [512][3136]->[j][p*64+oc]
        int g = blk * 256 + tidx;
        int j = g / 3136, kp = g % 3136, p = kp >> 6, oc = kp & 63;
        wfcP[g] = f2bf(fcw[j * 3136 + oc * 49 + p]);
        return;
    }
    blk -= 6272;
    if (blk < 2048) {                                   // wih: drop cols 512..528
        int g = blk * 256 + tidx;
        int r = g >> 9, k = g & 511;
        wihP[g] = f2bf(wih[r * 529 + k]);
        return;
    }
    blk -= 2048;
    if (blk < 32) {                                     // conv1 w
        int g = blk * 256 + tidx;
        int ky = g >> 10, oc = (g >> 5) & 31, k = g & 31, kx = k >> 2, ci = k & 3;
        wp1[g] = f2bf(c1w[((oc * 4 + ci) * 8 + ky) * 8 + kx]);
        return;
    }
    blk -= 32;
    if (blk < 128) {                                    // conv2 w
        int g = blk * 256 + tidx;
        int t = g >> 11, oc = (g >> 5) & 63, ci = g & 31, ky = t >> 2, kx = t & 3;
        wp2[g] = f2bf(c2w[((oc * 32 + ci) * 4 + ky) * 4 + kx]);
        return;
    }
    blk -= 128;
    {                                                   // conv3 w (144 blocks)
        int g = blk * 256 + tidx;
        int tkc = g >> 11, oc = (g >> 5) & 63, c32 = g & 31;
        int t = tkc >> 1, kc = tkc & 1, ky = t / 3, kx = t % 3;
        wp3[g] = f2bf(c3w[((oc * 64 + kc * 32 + c32) * 3 + ky) * 3 + kx]);
    }
}

// ================= conv1 MFMA: x[N,4,84,84] -> h1_cl[N,400,32] bf16 ==============
#define C1_RS 344            // 86 x-slots * 4 ci (entries per row)
__global__ __launch_bounds__(512) void conv1_mfma(
    const float* __restrict__ x, const short* __restrict__ wp1,  // [8][32][32]
    const float* __restrict__ bias, short* __restrict__ h1) {    // [N][400][32]
    __shared__ short xs[44 * C1_RS];      // 30.3 KB
    __shared__ short ob[208 * 32];        // 13.3 KB
    int blk = blockIdx.x, n = blk >> 1, h = blk & 1, tid = threadIdx.x;
    for (int i = tid; i < 44 * 84; i += 512) {   // one float4 (4 x-values) each
        int ry = i / 84, xi4 = i % 84;
        int ci = xi4 / 21, x4 = xi4 % 21;
        int iy = ry + h * 40 - 1;
        if (iy < 0 || iy > 83) continue;
        float4 v = *(const float4*)(x + (size_t)(n * 4 + ci) * 7056 + iy * 84 + x4 * 4);
        int base = ry * C1_RS + (x4 * 4 + 1) * 4 + ci;
        xs[base] = f2bf(v.x); xs[base + 4] = f2bf(v.y);
        xs[base + 8] = f2bf(v.z); xs[base + 12] = f2bf(v.w);
    }
    for (int i = tid; i < 44 * 4; i += 512)      // zero x-slot 0 (x = -1)
        xs[(i >> 2) * C1_RS + (i & 3)] = 0;
    if (h == 0) for (int i = tid; i < C1_RS; i += 512) xs[i] = 0;  // row iy=-1
    __syncthreads();

    int lane = tid & 63, wid = tid >> 6;
    int lr = lane & 15, kq = lane >> 4;
    short8 bfr[8][2];
#pragma unroll
    for (int ky = 0; ky < 8; ++ky)
#pragma unroll
        for (int nt = 0; nt < 2; ++nt)
            bfr[ky][nt] = *(const short8*)&wp1[((ky * 32) + nt * 16 + lr) * 32 + kq * 8];
    float b0 = bias[lr], b1 = bias[16 + lr];

    for (int t = wid; t < 13; t += 8) {
        int p = t * 16 + lr; if (p > 199) p = 199;       // clamp (masked at store)
        int oy = p / 20, ox = p % 20;
        f32x4 acc0 = {0.f, 0.f, 0.f, 0.f}, acc1 = {0.f, 0.f, 0.f, 0.f};
#pragma unroll
        for (int ky = 0; ky < 8; ++ky) {
            int ry = oy * 4 + ky;
            short8 af = *(const short8*)&xs[ry * C1_RS + ox * 16 + kq * 8];
            acc0 = MFMA16(af, bfr[ky][0], acc0);
            acc1 = MFMA16(af, bfr[ky][1], acc1);
        }
        int pm = t * 16 + kq * 4;
#pragma unroll
        for (int r = 0; r < 4; ++r) {
            ob[(pm + r) * 32 + lr]      = f2bf(lrelu(acc0[r] + b0));
            ob[(pm + r) * 32 + 16 + lr] = f2bf(lrelu(acc1[r] + b1));
        }
    }
    __syncthreads();
    uint4* dst = (uint4*)(h1 + (size_t)n * 12800 + h * 6400);
    for (int i = tid; i < 800; i += 512) dst[i] = ((uint4*)ob)[i];
}

// ======= fused conv2+conv3: h1_cl -> (LDS) -> h3_cl[N,49*64] bf16 ================
__global__ __launch_bounds__(512) void conv23_mfma(
    const short* __restrict__ h1,
    const short* __restrict__ wp2, const float* __restrict__ b2v,   // [16][64][32]
    const short* __restrict__ wp3, const float* __restrict__ b3v,   // [9][2][64][32]
    short* __restrict__ h3) {
    __shared__ short in_s[400 * 40];      // 32 KB (pix stride padded 32->40)
    __shared__ short ob2[96 * 72];        // 13.5 KB
    int n = blockIdx.x, tid = threadIdx.x;
    const uint4* src = (const uint4*)(h1 + (size_t)n * 12800);
    for (int i = tid; i < 1600; i += 512)
        *(uint4*)&in_s[(i >> 2) * 40 + (i & 3) * 8] = src[i];
    __syncthreads();
    int lane = tid & 63, wid = tid >> 6;
    int nt = wid & 3, mh = wid >> 2;
    int lr = lane & 15, kq = lane >> 4;
    {   // ---- phase A: conv2 ----
        short8 bfr[16];
#pragma unroll
        for (int t = 0; t < 16; ++t)
            bfr[t] = *(const short8*)&wp2[(t * 64 + nt * 16 + lr) * 32 + kq * 8];
        float bl = b2v[nt * 16 + lr];
        for (int mt = mh * 3; mt < mh * 3 + 3; ++mt) {
            int p = mt * 16 + lr; if (p > 80) p = 80;
            int oy = p / 9, ox = p % 9;
            f32x4 acc = {0.f, 0.f, 0.f, 0.f};
#pragma unroll
            for (int ky = 0; ky < 4; ++ky)
#pragma unroll
                for (int kx = 0; kx < 4; ++kx) {
                    int pix = (oy * 2 + ky) * 20 + ox * 2 + kx;
                    short8 af = *(const short8*)&in_s[pix * 40 + kq * 8];
                    acc = MFMA16(af, bfr[ky * 4 + kx], acc);
                }
            int pm = mt * 16 + kq * 4;
#pragma unroll
            for (int r = 0; r < 4; ++r)
                ob2[(pm + r) * 72 + nt * 16 + lr] = f2bf(lrelu(acc[r] + bl));
        }
    }
    __syncthreads();
    {   // ---- phase B: conv3 from ob2 (in_s reused as output bounce) ----
        short8 cfr[18];
#pragma unroll
        for (int t = 0; t < 18; ++t)
            cfr[t] = *(const short8*)&wp3[(t * 64 + nt * 16 + lr) * 32 + kq * 8];
        float bl3 = b3v[nt * 16 + lr];
        short* ob3 = in_s;
        for (int mt = mh * 2; mt < mh * 2 + 2; ++mt) {
            int p = mt * 16 + lr; if (p > 48) p = 48;
            int oy = p / 7, ox = p % 7;
            f32x4 acc = {0.f, 0.f, 0.f, 0.f};
#pragma unroll
            for (int ky = 0; ky < 3; ++ky)
#pragma unroll
                for (int kx = 0; kx < 3; ++kx) {
                    int pix = (oy + ky) * 9 + ox + kx;
#pragma unroll
                    for (int kc = 0; kc < 2; ++kc) {
                        short8 af = *(const short8*)&ob2[pix * 72 + kc * 32 + kq * 8];
                        acc = MFMA16(af, cfr[(ky * 3 + kx) * 2 + kc], acc);
                    }
                }
            int pm = mt * 16 + kq * 4;
#pragma unroll
            for (int r = 0; r < 4; ++r)
                ob3[(pm + r) * 64 + nt * 16 + lr] = f2bf(lrelu(acc[r] + bl3));
        }
    }
    __syncthreads();
    uint4* dst = (uint4*)(h3 + (size_t)n * 3136);
    for (int i = tid; i < 392; i += 512) dst[i] = ((uint4*)in_s)[i];
}

// ========== bf16 GEMM, tile 128x128: C[M,N] = A[M,K] @ B[N,K]^T =================
// OUT=1: +bias, lrelu, bf16 out.  OUT=2: fp32 out + fused LSTM-gates epilogue.
template <int OUT>
__global__ __launch_bounds__(256) void gemm_bf16(
    const short* __restrict__ A, const short* __restrict__ B,
    const float* __restrict__ bias, void* __restrict__ Cout,
    int M, int N, int K, int ldc,
    const float* __restrict__ reward = nullptr, const int* __restrict__ la = nullptr,
    const float* __restrict__ wih = nullptr, const float* __restrict__ bih = nullptr,
    const float* __restrict__ bhh = nullptr) {
    __shared__ short smem[20480];                    // As[2][5120] | Bs[2][5120]
    int m0 = blockIdx.y * 128, n0 = blockIdx.x * 128;
    int tid = threadIdx.x;
    int lane = tid & 63, wid = tid >> 6;
    int wr = wid >> 1, wc = wid & 1;
    int lr = lane & 15, kq = lane >> 4;
    f32x4 acc[4][4];
#pragma unroll
    for (int i = 0; i < 4; ++i)
#pragma unroll
        for (int j = 0; j < 4; ++j) acc[i][j] = (f32x4){0.f, 0.f, 0.f, 0.f};

    int nsteps = K >> 5;
#define STAGE(k0, buf)                                                          \
    {                                                                           \
        short* As = smem + (buf) * 5120;                                        \
        short* Bs = smem + 10240 + (buf) * 5120;                                \
        for (int i = tid; i < 512; i += 256) {                                  \
            int row = i >> 2, c4 = i & 3;                                       \
            *(uint4*)&As[row * 40 + c4 * 8] =                                   \
                *(const uint4*)&A[(size_t)(m0 + row) * K + (k0) + c4 * 8];      \
            *(uint4*)&Bs[row * 40 + c4 * 8] =                                   \
                *(const uint4*)&B[(size_t)(n0 + row) * K + (k0) + c4 * 8];      \
        }                                                                       \
    }
    STAGE(0, 0);
    __syncthreads();
    for (int ks = 0; ks < nsteps; ++ks) {
        int buf = ks & 1;
        if (ks + 1 < nsteps) STAGE((ks + 1) * 32, buf ^ 1);
        short* As = smem + buf * 5120;
        short* Bs = smem + 10240 + buf * 5120;
        short8 af[4], bfr[4];
#pragma unroll
        for (int i = 0; i < 4; ++i)
            af[i] = *(const short8*)&As[(wr * 64 + i * 16 + lr) * 40 + kq * 8];
#pragma unroll
        for (int j = 0; j < 4; ++j)
            bfr[j] = *(const short8*)&Bs[(wc * 64 + j * 16 + lr) * 40 + kq * 8];
#pragma unroll
        for (int i = 0; i < 4; ++i)
#pragma unroll
            for (int j = 0; j < 4; ++j)
                acc[i][j] = MFMA16(af[i], bfr[j], acc[i][j]);
        __syncthreads();
    }
#undef STAGE
    if (OUT == 2) {
        float* C = (float*)Cout;
#pragma unroll
        for (int i = 0; i < 4; ++i)
#pragma unroll
            for (int j = 0; j < 4; ++j) {
                int col = n0 + wc * 64 + j * 16 + lr;
                const float* wrow = wih + (size_t)col * 529;
                float base = bih[col] + bhh[col];
                float w512 = wrow[512];
#pragma unroll
                for (int r = 0; r < 4; ++r) {
                    int row = m0 + wr * 64 + i * 16 + kq * 4 + r;
                    C[(size_t)row * ldc + col] =
                        acc[i][j][r] + base + reward[row] * w512 + wrow[513 + la[row]];
                }
            }
    } else {
        short* ob = smem;                             // 128x128 bf16 bounce
#pragma unroll
        for (int i = 0; i < 4; ++i)
#pragma unroll
            for (int j = 0; j < 4; ++j) {
                int col = wc * 64 + j * 16 + lr;
                float bl = bias[n0 + col];
#pragma unroll
                for (int r = 0; r < 4; ++r) {
                    int row = wr * 64 + i * 16 + kq * 4 + r;
                    ob[row * 128 + col] = f2bf(lrelu(acc[i][j][r] + bl));
                }
            }
        __syncthreads();
        short* C = (short*)Cout;
        for (int i = tid; i < 2048; i += 256) {
            int row = i >> 4, c16 = i & 15;
            *(uint4*)&C[(size_t)(m0 + row) * ldc + n0 + c16 * 8] =
                *(uint4*)&ob[row * 128 + c16 * 8];
        }
    }
}

// ---------- LSTM v10: FULL Whh resident in ONE workgroup -> zero cross-WG sync ---
// 8 WGs (one per 4-batch group, blockIdx 0..7 = one per XCD), 1024 threads = 16
// waves = 4 waves/SIMD -> unified VGPR+AGPR budget 512/thread.  Wave w owns 64
// gate rows (gt=w>>2 gate type, s4=w&3 unit quarter) as bf16 MFMA A-frags:
// afr[4][8] short8 = 128 regs/thread (AGPR-resident per R7 evidence; total 512KB
// = full Whh).  Per step: MFMA from LDS hB -> gate_s -> pointwise writes h back
// into hB (bf16) directly.  2 __syncthreads/step, NO flags, NO hpub, NO L2.
__global__ __launch_bounds__(1024, 1) void lstm8_k(
    const float* __restrict__ gx,        // [N_,1024]
    const float* __restrict__ whh,       // [1024,256] fp32
    const unsigned char* __restrict__ dones,
    const float* __restrict__ hx,        // [2,B_,256]
    float* __restrict__ hs) {            // [N_,256]
    const int tid = threadIdx.x;
    const int grp = blockIdx.x;          // batches grp*4..+3
    const int lane = tid & 63, w = tid >> 6;      // 16 waves
    const int gt = w >> 2, s4 = w & 3;
    const int lr = lane & 15, kq = lane >> 4;

    __shared__ short hB[16 * 264];       // [batch 16 (4 real)][k 256 +8 pad]
    __shared__ float gate_s[4][256][4];  // [gate][unit][batch]  16 KB

    // ---- resident A-frags: row = gt*256 + s4*64 + mi*16 + lr ----
    short8 afr[4][8];
#pragma unroll
    for (int mi = 0; mi < 4; ++mi) {
        int row = gt * 256 + s4 * 64 + mi * 16 + lr;
        const float* wrp = whh + (size_t)row * 256;
#pragma unroll
        for (int kt = 0; kt < 8; ++kt) {
            int k0 = kt * 32 + kq * 8;
            float4 a = *(const float4*)(wrp + k0);
            float4 b = *(const float4*)(wrp + k0 + 4);
            short8 f;
            f[0] = f2bf(a.x); f[1] = f2bf(a.y); f[2] = f2bf(a.z); f[3] = f2bf(a.w);
            f[4] = f2bf(b.x); f[5] = f2bf(b.y); f[6] = f2bf(b.z); f[7] = f2bf(b.w);
            afr[mi][kt] = f;
        }
    }
    {   // pin against rematerialization (R2/R3/R5 lesson)
        int* ap = (int*)afr;
#pragma unroll
        for (int i = 0; i < 128; ++i) asm volatile("" : "+v"(ap[i]));
    }

    // zero unused B rows 4..15 once
    for (int i = tid; i < 12 * 264; i += 1024) hB[4 * 264 + i] = 0;

    const int u = tid >> 2, bt = tid & 3;        // pointwise ownership: unit,batch
    const int b = grp * 4 + bt;
    float cc = hx[(size_t)B_ * LH_ + b * LH_ + u];

    // ---- t=1 staging from hx (1024 threads, one value each) ----
    {
        int bt2 = tid >> 8, k = tid & 255;
        int b2 = grp * 4 + bt2;
        float hv = hx[b2 * LH_ + k];
        if (dones[b2]) hv = 0.f;
        hB[bt2 * 264 + k] = f2bf(hv);
    }
    __syncthreads();

    for (int t = 1; t <= T_; ++t) {
        const int nb0 = (t - 1) * B_;
        // ---- prefetch gx (independent of h; hides under MFMA phase) ----
        float gxv[4];
#pragma unroll
        for (int g2 = 0; g2 < 4; ++g2)
            gxv[g2] = gx[(size_t)(nb0 + b) * 1024 + g2 * 256 + u];

        // ---- MFMA: 64 gate rows x 4 batches per wave ----
        f32x4 acc[4] = {{0.f,0.f,0.f,0.f},{0.f,0.f,0.f,0.f},
                        {0.f,0.f,0.f,0.f},{0.f,0.f,0.f,0.f}};
#pragma unroll
        for (int kt = 0; kt < 8; ++kt) {
            short8 bfr = *(const short8*)&hB[lr * 264 + kt * 32 + kq * 8];
#pragma unroll
            for (int mi = 0; mi < 4; ++mi)
                acc[mi] = MFMA16(afr[mi][kt], bfr, acc[mi]);
        }
        if (lr < 4) {                                // cols 0..3 = real batches
#pragma unroll
            for (int mi = 0; mi < 4; ++mi)
#pragma unroll
                for (int r = 0; r < 4; ++r)
                    gate_s[gt][s4 * 64 + mi * 16 + kq * 4 + r][lr] = acc[mi][r];
        }
        __syncthreads();                             // gates done; hB reads done

        // ---- pointwise: 256 units x 4 batches == 1024 threads ----
        {
            bool dn = dones[nb0 + b] != 0;
            float gi = gate_s[0][u][bt] + gxv[0];
            float gf = gate_s[1][u][bt] + gxv[1];
            float gg = gate_s[2][u][bt] + gxv[2];
            float go = gate_s[3][u][bt] + gxv[3];
            float ccv = dn ? 0.f : cc;
            float si = 1.f / (1.f + expf(-gi));
            float sf = 1.f / (1.f + expf(-gf));
            float so = 1.f / (1.f + expf(-go));
            float c2 = sf * ccv + si * tanhf(gg);
            float h2 = so * tanhf(c2);
            cc = c2;
            hs[(size_t)(nb0 + b) * LH_ + u] = h2;
            if (t < T_) {                            // write h(t) for next step,
                float hm = dones[t * B_ + b] ? 0.f : h2;   // pre-masked
                hB[bt * 264 + u] = f2bf(hm);
            }
        }
        __syncthreads();                             // hB(t) ready for next MFMA
    }
}

// ---------- heads ----------
__global__ void head_k(const float* __restrict__ hs,
                       const float* __restrict__ aw, const float* __restrict__ ab,
                       const float* __restrict__ cw, const float* __restrict__ cb,
                       float* __restrict__ out) {
    int gid = blockIdx.x * 256 + threadIdx.x;       // N_*17
    if (gid >= N_ * 17) return;
    int n = gid / 17, r = gid % 17;
    const float* f = hs + (size_t)n * 256;
    if (r < 16) {
        const float* w = aw + r * 256;
        float acc = ab[r];
        for (int k = 0; k < 256; ++k) acc = fmaf(f[k], w[k], acc);
        if (isnan(acc)) acc = 1e-12f;
        out[(size_t)n * 16 + r] = acc;
    } else {
        float acc = cb[0];
        for (int k = 0; k < 256; ++k) acc = fmaf(f[k], cw[k], acc);
        out[(size_t)N_ * 16 + n] = acc;
    }
}

extern "C" void kernel_launch(void* const* d_in, const int* in_sizes, int n_in,
                              void* d_out, int out_size, void* d_ws, size_t ws_size,
                              hipStream_t stream) {
    const float* x      = (const float*)d_in[0];
    const int* la       = (const int*)d_in[1];
    const float* reward = (const float*)d_in[2];
    const unsigned char* dones = (const unsigned char*)d_in[3];
    const float* hx     = (const float*)d_in[4];
    const float* c1w = (const float*)d_in[5];  const float* c1b = (const float*)d_in[6];
    const float* c2w = (const float*)d_in[7];  const float* c2b = (const float*)d_in[8];
    const float* c3w = (const float*)d_in[9];  const float* c3b = (const float*)d_in[10];
    const float* fcw = (const float*)d_in[11]; const float* fcb = (const float*)d_in[12];
    const float* wih = (const float*)d_in[13]; const float* whh = (const float*)d_in[14];
    const float* bih = (const float*)d_in[15]; const float* bhh = (const float*)d_in[16];
    const float* aw  = (const float*)d_in[17]; const float* ab  = (const float*)d_in[18];
    const float* cw  = (const float*)d_in[19]; const float* cb  = (const float*)d_in[20];

    char* wsb = (char*)d_ws;
    short* h1   = (short*)(wsb);                         // 65,536,000 B
    short* h3   = (short*)(wsb + 92078080);              // 16,056,320
    short* hfc  = (short*)(wsb + 108134400);             //  2,621,440
    float* gx   = (float*)(wsb + 110755840);             // 10,485,760
    float* hs   = (float*)(wsb + 121241600);             //  2,621,440
    short* wp1  = (short*)(wsb + 123932672);             //     16,384
    short* wp2  = (short*)(wsb + 123949056);             //     65,536
    short* wp3  = (short*)(wsb + 124014592);             //     73,728
    short* wfcP = (short*)(wsb + 124088320);             //  3,211,264
    short* wihP = (short*)(wsb + 127299584);             //  1,048,576

    pack_all_k<<<8624, 256, 0, stream>>>(c1w, c2w, c3w, fcw, wih,
                                         wp1, wp2, wp3, wfcP, wihP);

    conv1_mfma<<<5120, 512, 0, stream>>>(x, wp1, c1b, h1);
    conv23_mfma<<<2560, 512, 0, stream>>>(h1, wp2, c2b, wp3, c3b, h3);

    gemm_bf16<1><<<dim3(4, 20), 256, 0, stream>>>(h3, wfcP, fcb, hfc,
                                                  2560, 512, 3136, 512);
    gemm_bf16<2><<<dim3(8, 20), 256, 0, stream>>>(hfc, wihP, nullptr, gx,
                                                  2560, 1024, 512, 1024,
                                                  reward, la, wih, bih, bhh);

    lstm8_k<<<8, 1024, 0, stream>>>(gx, whh, dones, hx, hs);
    head_k<<<170, 256, 0, stream>>>(hs, aw, ab, cw, cb, (float*)d_out);
}

// Round 11
// 528.614 us; speedup vs baseline: 1.5639x; 1.5639x over previous
//
#include <hip/hip_runtime.h>
#include <math.h>

#define T_ 80
#define B_ 32
#define N_ 2560            // T_*B_
#define LH_ 256

typedef __attribute__((ext_vector_type(8))) short short8;
typedef __attribute__((ext_vector_type(4))) float f32x4;
#define MFMA16(a, b, c) __builtin_amdgcn_mfma_f32_16x16x32_bf16((a), (b), (c), 0, 0, 0)

__device__ __forceinline__ float lrelu(float v) { return v > 0.f ? v : 0.01f * v; }
__device__ __forceinline__ short f2bf(float f) {        // RNE float->bf16 bits
    unsigned u = __float_as_uint(f);
    return (short)((u + 0x7fffu + ((u >> 16) & 1u)) >> 16);
}

// ========== fused weight-pack + flag-zero (one kernel) ==========================
__global__ void pack_all_k(const float* __restrict__ c1w, const float* __restrict__ c2w,
                           const float* __restrict__ c3w, const float* __restrict__ fcw,
                           const float* __restrict__ wih,
                           short* __restrict__ wp1, short* __restrict__ wp2,
                           short* __restrict__ wp3, short* __restrict__ wfcP,
                           short* __restrict__ wihP, int* __restrict__ cnt) {
    int blk = blockIdx.x, tidx = threadIdx.x;
    if (blk < 6272) {                                   // fc: [512][3136]->[j][p*64+oc]
        int g = blk * 256 + tidx;
        int j = g / 3136, kp = g % 3136, p = kp >> 6, oc = kp & 63;
        wfcP[g] = f2bf(fcw[j * 3136 + oc * 49 + p]);
        return;
    }
    blk -= 6272;
    if (blk < 2048) {                                   // wih: drop cols 512..528
        int g = blk * 256 + tidx;
        int r = g >> 9, k = g & 511;
        wihP[g] = f2bf(wih[r * 529 + k]);
        return;
    }
    blk -= 2048;
    if (blk < 32) {                                     // conv1 w
        int g = blk * 256 + tidx;
        int ky = g >> 10, oc = (g >> 5) & 31, k = g & 31, kx = k >> 2, ci = k & 3;
        wp1[g] = f2bf(c1w[((oc * 4 + ci) * 8 + ky) * 8 + kx]);
        return;
    }
    blk -= 32;
    if (blk < 128) {                                    // conv2 w
        int g = blk * 256 + tidx;
        int t = g >> 11, oc = (g >> 5) & 63, ci = g & 31, ky = t >> 2, kx = t & 3;
        wp2[g] = f2bf(c2w[((oc * 32 + ci) * 4 + ky) * 4 + kx]);
        return;
    }
    blk -= 128;
    if (blk < 144) {                                    // conv3 w
        int g = blk * 256 + tidx;
        int tkc = g >> 11, oc = (g >> 5) & 63, c32 = g & 31;
        int t = tkc >> 1, kc = tkc & 1, ky = t / 3, kx = t % 3;
        wp3[g] = f2bf(c3w[((oc * 64 + kc * 32 + c32) * 3 + ky) * 3 + kx]);
        return;
    }
    cnt[tidx] = 0; cnt[256 + tidx] = 0;                 // 512 ints of sync counters
}

// ================= conv1 MFMA: x[N,4,84,84] -> h1_cl[N,400,32] bf16 ==============
#define C1_RS 344            // 86 x-slots * 4 ci (entries per row)
__global__ __launch_bounds__(512) void conv1_mfma(
    const float* __restrict__ x, const short* __restrict__ wp1,  // [8][32][32]
    const float* __restrict__ bias, short* __restrict__ h1) {    // [N][400][32]
    __shared__ short xs[44 * C1_RS];      // 30.3 KB
    __shared__ short ob[208 * 32];        // 13.3 KB
    int blk = blockIdx.x, n = blk >> 1, h = blk & 1, tid = threadIdx.x;
    for (int i = tid; i < 44 * 84; i += 512) {   // one float4 (4 x-values) each
        int ry = i / 84, xi4 = i % 84;
        int ci = xi4 / 21, x4 = xi4 % 21;
        int iy = ry + h * 40 - 1;
        if (iy < 0 || iy > 83) continue;
        float4 v = *(const float4*)(x + (size_t)(n * 4 + ci) * 7056 + iy * 84 + x4 * 4);
        int base = ry * C1_RS + (x4 * 4 + 1) * 4 + ci;
        xs[base] = f2bf(v.x); xs[base + 4] = f2bf(v.y);
        xs[base + 8] = f2bf(v.z); xs[base + 12] = f2bf(v.w);
    }
    for (int i = tid; i < 44 * 4; i += 512)      // zero x-slot 0 (x = -1)
        xs[(i >> 2) * C1_RS + (i & 3)] = 0;
    if (h == 0) for (int i = tid; i < C1_RS; i += 512) xs[i] = 0;  // row iy=-1
    __syncthreads();

    int lane = tid & 63, wid = tid >> 6;
    int lr = lane & 15, kq = lane >> 4;
    short8 bfr[8][2];
#pragma unroll
    for (int ky = 0; ky < 8; ++ky)
#pragma unroll
        for (int nt = 0; nt < 2; ++nt)
            bfr[ky][nt] = *(const short8*)&wp1[((ky * 32) + nt * 16 + lr) * 32 + kq * 8];
    float b0 = bias[lr], b1 = bias[16 + lr];

    for (int t = wid; t < 13; t += 8) {
        int p = t * 16 + lr; if (p > 199) p = 199;       // clamp (masked at store)
        int oy = p / 20, ox = p % 20;
        f32x4 acc0 = {0.f, 0.f, 0.f, 0.f}, acc1 = {0.f, 0.f, 0.f, 0.f};
#pragma unroll
        for (int ky = 0; ky < 8; ++ky) {
            int ry = oy * 4 + ky;
            short8 af = *(const short8*)&xs[ry * C1_RS + ox * 16 + kq * 8];
            acc0 = MFMA16(af, bfr[ky][0], acc0);
            acc1 = MFMA16(af, bfr[ky][1], acc1);
        }
        int pm = t * 16 + kq * 4;
#pragma unroll
        for (int r = 0; r < 4; ++r) {
            ob[(pm + r) * 32 + lr]      = f2bf(lrelu(acc0[r] + b0));
            ob[(pm + r) * 32 + 16 + lr] = f2bf(lrelu(acc1[r] + b1));
        }
    }
    __syncthreads();
    uint4* dst = (uint4*)(h1 + (size_t)n * 12800 + h * 6400);
    for (int i = tid; i < 800; i += 512) dst[i] = ((uint4*)ob)[i];
}

// ======= fused conv2+conv3: h1_cl -> (LDS) -> h3_cl[N,49*64] bf16 ================
__global__ __launch_bounds__(512) void conv23_mfma(
    const short* __restrict__ h1,
    const short* __restrict__ wp2, const float* __restrict__ b2v,   // [16][64][32]
    const short* __restrict__ wp3, const float* __restrict__ b3v,   // [9][2][64][32]
    short* __restrict__ h3) {
    __shared__ short in_s[400 * 40];      // 32 KB (pix stride padded 32->40)
    __shared__ short ob2[96 * 72];        // 13.5 KB
    int n = blockIdx.x, tid = threadIdx.x;
    const uint4* src = (const uint4*)(h1 + (size_t)n * 12800);
    for (int i = tid; i < 1600; i += 512)
        *(uint4*)&in_s[(i >> 2) * 40 + (i & 3) * 8] = src[i];
    __syncthreads();
    int lane = tid & 63, wid = tid >> 6;
    int nt = wid & 3, mh = wid >> 2;
    int lr = lane & 15, kq = lane >> 4;
    {   // ---- phase A: conv2 ----
        short8 bfr[16];
#pragma unroll
        for (int t = 0; t < 16; ++t)
            bfr[t] = *(const short8*)&wp2[(t * 64 + nt * 16 + lr) * 32 + kq * 8];
        float bl = b2v[nt * 16 + lr];
        for (int mt = mh * 3; mt < mh * 3 + 3; ++mt) {
            int p = mt * 16 + lr; if (p > 80) p = 80;
            int oy = p / 9, ox = p % 9;
            f32x4 acc = {0.f, 0.f, 0.f, 0.f};
#pragma unroll
            for (int ky = 0; ky < 4; ++ky)
#pragma unroll
                for (int kx = 0; kx < 4; ++kx) {
                    int pix = (oy * 2 + ky) * 20 + ox * 2 + kx;
                    short8 af = *(const short8*)&in_s[pix * 40 + kq * 8];
                    acc = MFMA16(af, bfr[ky * 4 + kx], acc);
                }
            int pm = mt * 16 + kq * 4;
#pragma unroll
            for (int r = 0; r < 4; ++r)
                ob2[(pm + r) * 72 + nt * 16 + lr] = f2bf(lrelu(acc[r] + bl));
        }
    }
    __syncthreads();
    {   // ---- phase B: conv3 from ob2 (in_s reused as output bounce) ----
        short8 cfr[18];
#pragma unroll
        for (int t = 0; t < 18; ++t)
            cfr[t] = *(const short8*)&wp3[(t * 64 + nt * 16 + lr) * 32 + kq * 8];
        float bl3 = b3v[nt * 16 + lr];
        short* ob3 = in_s;
        for (int mt = mh * 2; mt < mh * 2 + 2; ++mt) {
            int p = mt * 16 + lr; if (p > 48) p = 48;
            int oy = p / 7, ox = p % 7;
            f32x4 acc = {0.f, 0.f, 0.f, 0.f};
#pragma unroll
            for (int ky = 0; ky < 3; ++ky)
#pragma unroll
                for (int kx = 0; kx < 3; ++kx) {
                    int pix = (oy + ky) * 9 + ox + kx;
#pragma unroll
                    for (int kc = 0; kc < 2; ++kc) {
                        short8 af = *(const short8*)&ob2[pix * 72 + kc * 32 + kq * 8];
                        acc = MFMA16(af, cfr[(ky * 3 + kx) * 2 + kc], acc);
                    }
                }
            int pm = mt * 16 + kq * 4;
#pragma unroll
            for (int r = 0; r < 4; ++r)
                ob3[(pm + r) * 64 + nt * 16 + lr] = f2bf(lrelu(acc[r] + bl3));
        }
    }
    __syncthreads();
    uint4* dst = (uint4*)(h3 + (size_t)n * 3136);
    for (int i = tid; i < 392; i += 512) dst[i] = ((uint4*)in_s)[i];
}

// ========== bf16 GEMM, tile 128x64 (better CU coverage): C = A @ B^T ============
// OUT=1: +bias, lrelu, bf16 out.  OUT=2: fp32 out + fused LSTM-gates epilogue.
// 4 waves: wr=wid>>1 M-half(64), wc=wid&1 N-half(32); acc[4][2].
template <int OUT>
__global__ __launch_bounds__(256) void gemm_bf16(
    const short* __restrict__ A, const short* __restrict__ B,
    const float* __restrict__ bias, void* __restrict__ Cout,
    int M, int N, int K, int ldc,
    const float* __restrict__ reward = nullptr, const int* __restrict__ la = nullptr,
    const float* __restrict__ wih = nullptr, const float* __restrict__ bih = nullptr,
    const float* __restrict__ bhh = nullptr) {
    __shared__ short smem[15360];            // As[2][5120] | Bs[2][2560]
    int m0 = blockIdx.y * 128, n0 = blockIdx.x * 64;
    int tid = threadIdx.x;
    int lane = tid & 63, wid = tid >> 6;
    int wr = wid >> 1, wc = wid & 1;
    int lr = lane & 15, kq = lane >> 4;
    f32x4 acc[4][2];
#pragma unroll
    for (int i = 0; i < 4; ++i)
#pragma unroll
        for (int j = 0; j < 2; ++j) acc[i][j] = (f32x4){0.f, 0.f, 0.f, 0.f};

    int nsteps = K >> 5;
#define STAGE(k0, buf)                                                          \
    {                                                                           \
        short* As = smem + (buf) * 5120;                                        \
        short* Bs = smem + 10240 + (buf) * 2560;                                \
        for (int i = tid; i < 512; i += 256) {                                  \
            int row = i >> 2, c4 = i & 3;                                       \
            *(uint4*)&As[row * 40 + c4 * 8] =                                   \
                *(const uint4*)&A[(size_t)(m0 + row) * K + (k0) + c4 * 8];      \
        }                                                                       \
        {                                                                       \
            int row = tid >> 2, c4 = tid & 3;                                   \
            *(uint4*)&Bs[row * 40 + c4 * 8] =                                   \
                *(const uint4*)&B[(size_t)(n0 + row) * K + (k0) + c4 * 8];      \
        }                                                                       \
    }
    STAGE(0, 0);
    __syncthreads();
    for (int ks = 0; ks < nsteps; ++ks) {
        int buf = ks & 1;
        if (ks + 1 < nsteps) STAGE((ks + 1) * 32, buf ^ 1);
        short* As = smem + buf * 5120;
        short* Bs = smem + 10240 + buf * 2560;
        short8 af[4], bfr[2];
#pragma unroll
        for (int i = 0; i < 4; ++i)
            af[i] = *(const short8*)&As[(wr * 64 + i * 16 + lr) * 40 + kq * 8];
#pragma unroll
        for (int j = 0; j < 2; ++j)
            bfr[j] = *(const short8*)&Bs[(wc * 32 + j * 16 + lr) * 40 + kq * 8];
#pragma unroll
        for (int i = 0; i < 4; ++i)
#pragma unroll
            for (int j = 0; j < 2; ++j)
                acc[i][j] = MFMA16(af[i], bfr[j], acc[i][j]);
        __syncthreads();
    }
#undef STAGE
    if (OUT == 2) {
        float* C = (float*)Cout;
#pragma unroll
        for (int i = 0; i < 4; ++i)
#pragma unroll
            for (int j = 0; j < 2; ++j) {
                int col = n0 + wc * 32 + j * 16 + lr;
                const float* wrow = wih + (size_t)col * 529;
                float base = bih[col] + bhh[col];
                float w512 = wrow[512];
#pragma unroll
                for (int r = 0; r < 4; ++r) {
                    int row = m0 + wr * 64 + i * 16 + kq * 4 + r;
                    C[(size_t)row * ldc + col] =
                        acc[i][j][r] + base + reward[row] * w512 + wrow[513 + la[row]];
                }
            }
    } else {
        short* ob = smem;                             // 128x64 bf16 bounce
#pragma unroll
        for (int i = 0; i < 4; ++i)
#pragma unroll
            for (int j = 0; j < 2; ++j) {
                int col = wc * 32 + j * 16 + lr;
                float bl = bias[n0 + col];
#pragma unroll
                for (int r = 0; r < 4; ++r) {
                    int row = wr * 64 + i * 16 + kq * 4 + r;
                    ob[row * 64 + col] = f2bf(lrelu(acc[i][j][r] + bl));
                }
            }
        __syncthreads();
        short* C = (short*)Cout;
        for (int i = tid; i < 1024; i += 256) {
            int row = i >> 3, c8 = i & 7;
            *(uint4*)&C[(size_t)(m0 + row) * ldc + n0 + c8 * 8] =
                *(uint4*)&ob[row * 64 + c8 * 8];
        }
    }
}

// ---------- LSTM v11: R9 structure + lean exchange ------------------------------
// R9's proven core (16 WGs = 8 grp x 2 half, tid==0 acquire-spin + barrier
// fan-out, resident A-frags) with: (a) bf16 hpub (publisher stores the same bits
// staging would compute -- zero added rounding); (b) pointwise writes own half
// straight into hB (own units never cross L2); (c) t>1 staging touches only the
// peer's 512 ushorts, pre-masked at publish.
__global__ __launch_bounds__(512) void lstm16_k(
    const float* __restrict__ gx,        // [N_,1024]
    const float* __restrict__ whh,       // [1024,256] fp32
    const unsigned char* __restrict__ dones,
    const float* __restrict__ hx,        // [2,B_,256]
    float* __restrict__ hs,              // [N_,256]
    unsigned short* __restrict__ hpub,   // [2][B_][256] bf16 ping-pong
    int* __restrict__ cnt) {             // [(grp*2+half)*32]
    const int tid = threadIdx.x;
    const int grp  = blockIdx.x & 7;     // batch group (== XCD), batches grp*4..+3
    const int half = blockIdx.x >> 3;    // hidden half: units half*128..+127
    const int lane = tid & 63, w = tid >> 6;
    const int gt = w >> 1, s2 = w & 1;
    const int lr = lane & 15, kq = lane >> 4;

    __shared__ short hB[16 * 264];       // [batch 16][k 256 +8 pad] bf16
    __shared__ float gate_s[4][128][4];  // [gate][unit][batch]

    // ---- resident A-frags: afr[mi][kt], row = gt*256+half*128+s2*64+mi*16+lr ----
    short8 afr[4][8];
#pragma unroll
    for (int mi = 0; mi < 4; ++mi) {
        int row = gt * 256 + half * 128 + s2 * 64 + mi * 16 + lr;
        const float* wr = whh + (size_t)row * 256;
#pragma unroll
        for (int kt = 0; kt < 8; ++kt) {
            int k0 = kt * 32 + kq * 8;
            float4 a = *(const float4*)(wr + k0);
            float4 b = *(const float4*)(wr + k0 + 4);
            short8 f;
            f[0] = f2bf(a.x); f[1] = f2bf(a.y); f[2] = f2bf(a.z); f[3] = f2bf(a.w);
            f[4] = f2bf(b.x); f[5] = f2bf(b.y); f[6] = f2bf(b.z); f[7] = f2bf(b.w);
            afr[mi][kt] = f;
        }
    }
    {   // pin against rematerialization (R2/R3/R5 lesson)
        int* ap = (int*)afr;
#pragma unroll
        for (int i = 0; i < 128; ++i) asm volatile("" : "+v"(ap[i]));
    }

    // zero unused B rows 4..15 once
    for (int i = tid; i < 12 * 264; i += 512) hB[4 * 264 + i] = 0;

    const int u = tid >> 2, bt = tid & 3;        // pointwise ownership
    const int b = grp * 4 + bt, gu = half * 128 + u;
    float cc = hx[(size_t)B_ * LH_ + b * LH_ + gu];

    // ---- t=1 staging: both halves from hx, dones[0] mask ----
#pragma unroll
    for (int l = 0; l < 2; ++l) {
        int e = tid + l * 512;                   // 0..1023
        int bt2 = e >> 8, k = e & 255;
        int b2 = grp * 4 + bt2;
        float hv = hx[b2 * LH_ + k];
        if (dones[b2]) hv = 0.f;
        hB[bt2 * 264 + k] = f2bf(hv);
    }
    __syncthreads();

    const int mycnt = (grp * 2 + half) * 32, peercnt = (grp * 2 + (half ^ 1)) * 32;
    const int phalf = (half ^ 1) << 7;           // peer's unit base

    for (int t = 1; t <= T_; ++t) {
        const int nb0 = (t - 1) * B_;
        // ---- prefetch gx for pointwise (independent of h) ----
        float gxv[4];
#pragma unroll
        for (int g2 = 0; g2 < 4; ++g2)
            gxv[g2] = gx[(size_t)(nb0 + b) * 1024 + g2 * 256 + gu];

        // ---- wait: peer finished step t-1; stage ONLY peer half ----
        if (t > 1) {
            if (tid == 0) {
                while (__hip_atomic_load(&cnt[peercnt], __ATOMIC_ACQUIRE,
                                         __HIP_MEMORY_SCOPE_AGENT) < t - 1)
                    __builtin_amdgcn_s_sleep(1);
            }
            __syncthreads();
            int bt2 = tid >> 7, pu = tid & 127;      // 4 batches x 128 units
            int b2 = grp * 4 + bt2, pgu = phalf + pu;
            hB[bt2 * 264 + pgu] =
                (short)hpub[((t - 1) & 1) * 8192 + b2 * 256 + pgu];
        }
        __syncthreads();                             // hB complete

        // ---- MFMA: G[64 rows][16 cols(4 used)] per wave ----
        f32x4 acc[4] = {{0.f,0.f,0.f,0.f},{0.f,0.f,0.f,0.f},
                        {0.f,0.f,0.f,0.f},{0.f,0.f,0.f,0.f}};
#pragma unroll
        for (int kt = 0; kt < 8; ++kt) {
            short8 bfr = *(const short8*)&hB[lr * 264 + kt * 32 + kq * 8];
#pragma unroll
            for (int mi = 0; mi < 4; ++mi)
                acc[mi] = MFMA16(afr[mi][kt], bfr, acc[mi]);
        }
        if (lr < 4) {                                // cols 0..3 = real batches
#pragma unroll
            for (int mi = 0; mi < 4; ++mi)
#pragma unroll
                for (int r = 0; r < 4; ++r)
                    gate_s[gt][s2 * 64 + mi * 16 + kq * 4 + r][lr] = acc[mi][r];
        }
        __syncthreads();                             // gates done; hB reads done

        // ---- pointwise: 128 units x 4 batches == 512 threads ----
        {
            bool dn = dones[nb0 + b] != 0;
            float gi = gate_s[0][u][bt] + gxv[0];
            float gf = gate_s[1][u][bt] + gxv[1];
            float gg = gate_s[2][u][bt] + gxv[2];
            float go = gate_s[3][u][bt] + gxv[3];
            float ccv = dn ? 0.f : cc;
            float si = 1.f / (1.f + expf(-gi));
            float sf = 1.f / (1.f + expf(-gf));
            float so = 1.f / (1.f + expf(-go));
            float c2 = sf * ccv + si * tanhf(gg);
            float h2 = so * tanhf(c2);
            cc = c2;
            hs[(size_t)(nb0 + b) * LH_ + gu] = h2;
            if (t < T_) {
                short hm = f2bf(dones[t * B_ + b] ? 0.f : h2);  // pre-masked t+1
                hB[bt * 264 + gu] = hm;                         // own half local
                hpub[(t & 1) * 8192 + b * 256 + gu] = (unsigned short)hm;
            }
        }
        __syncthreads();   // all hpub/hB stores drained before publish
        if (tid == 0)
            __hip_atomic_store(&cnt[mycnt], t, __ATOMIC_RELEASE,
                               __HIP_MEMORY_SCOPE_AGENT);
    }
}

// ---------- heads ----------
__global__ void head_k(const float* __restrict__ hs,
                       const float* __restrict__ aw, const float* __restrict__ ab,
                       const float* __restrict__ cw, const float* __restrict__ cb,
                       float* __restrict__ out) {
    int gid = blockIdx.x * 256 + threadIdx.x;       // N_*17
    if (gid >= N_ * 17) return;
    int n = gid / 17, r = gid % 17;
    const float* f = hs + (size_t)n * 256;
    if (r < 16) {
        const float* w = aw + r * 256;
        float acc = ab[r];
        for (int k = 0; k < 256; ++k) acc = fmaf(f[k], w[k], acc);
        if (isnan(acc)) acc = 1e-12f;
        out[(size_t)n * 16 + r] = acc;
    } else {
        float acc = cb[0];
        for (int k = 0; k < 256; ++k) acc = fmaf(f[k], cw[k], acc);
        out[(size_t)N_ * 16 + n] = acc;
    }
}

extern "C" void kernel_launch(void* const* d_in, const int* in_sizes, int n_in,
                              void* d_out, int out_size, void* d_ws, size_t ws_size,
                              hipStream_t stream) {
    const float* x      = (const float*)d_in[0];
    const int* la       = (const int*)d_in[1];
    const float* reward = (const float*)d_in[2];
    const unsigned char* dones = (const unsigned char*)d_in[3];
    const float* hx     = (const float*)d_in[4];
    const float* c1w = (const float*)d_in[5];  const float* c1b = (const float*)d_in[6];
    const float* c2w = (const float*)d_in[7];  const float* c2b = (const float*)d_in[8];
    const float* c3w = (const float*)d_in[9];  const float* c3b = (const float*)d_in[10];
    const float* fcw = (const float*)d_in[11]; const float* fcb = (const float*)d_in[12];
    const float* wih = (const float*)d_in[13]; const float* whh = (const float*)d_in[14];
    const float* bih = (const float*)d_in[15]; const float* bhh = (const float*)d_in[16];
    const float* aw  = (const float*)d_in[17]; const float* ab  = (const float*)d_in[18];
    const float* cw  = (const float*)d_in[19]; const float* cb  = (const float*)d_in[20];

    char* wsb = (char*)d_ws;
    short* h1   = (short*)(wsb);                         // 65,536,000 B
    short* h3   = (short*)(wsb + 92078080);              // 16,056,320
    short* hfc  = (short*)(wsb + 108134400);             //  2,621,440
    float* gx   = (float*)(wsb + 110755840);             // 10,485,760
    float* hs   = (float*)(wsb + 121241600);             //  2,621,440
    unsigned short* hpub = (unsigned short*)(wsb + 123863040);  // 32,768
    int*   cnt  = (int*)  (wsb + 123928576);             //      2,048 (16 ctr x 128B)
    short* wp1  = (short*)(wsb + 123932672);             //     16,384
    short* wp2  = (short*)(wsb + 123949056);             //     65,536
    short* wp3  = (short*)(wsb + 124014592);             //     73,728
    short* wfcP = (short*)(wsb + 124088320);             //  3,211,264
    short* wihP = (short*)(wsb + 127299584);             //  1,048,576

    pack_all_k<<<8625, 256, 0, stream>>>(c1w, c2w, c3w, fcw, wih,
                                         wp1, wp2, wp3, wfcP, wihP, cnt);

    conv1_mfma<<<5120, 512, 0, stream>>>(x, wp1, c1b, h1);
    conv23_mfma<<<2560, 512, 0, stream>>>(h1, wp2, c2b, wp3, c3b, h3);

    gemm_bf16<1><<<dim3(8, 20), 256, 0, stream>>>(h3, wfcP, fcb, hfc,
                                                  2560, 512, 3136, 512);
    gemm_bf16<2><<<dim3(16, 20), 256, 0, stream>>>(hfc, wihP, nullptr, gx,
                                                   2560, 1024, 512, 1024,
                                                   reward, la, wih, bih, bhh);

    lstm16_k<<<16, 512, 0, stream>>>(gx, whh, dones, hx, hs, hpub, cnt);
    head_k<<<170, 256, 0, stream>>>(hs, aw, ab, cw, cb, (float*)d_out);
}

// Round 12
// 485.607 us; speedup vs baseline: 1.7024x; 1.0886x over previous
//
#include <hip/hip_runtime.h>
#include <math.h>

#define T_ 80
#define B_ 32
#define N_ 2560            // T_*B_
#define LH_ 256

typedef __attribute__((ext_vector_type(8))) short short8;
typedef __attribute__((ext_vector_type(4))) float f32x4;
#define MFMA16(a, b, c) __builtin_amdgcn_mfma_f32_16x16x32_bf16((a), (b), (c), 0, 0, 0)

__device__ __forceinline__ float lrelu(float v) { return v > 0.f ? v : 0.01f * v; }
__device__ __forceinline__ short f2bf(float f) {        // RNE float->bf16 bits
    unsigned u = __float_as_uint(f);
    return (short)((u + 0x7fffu + ((u >> 16) & 1u)) >> 16);
}

// ========== fused weight-pack + flag-zero (one kernel) ==========================
__global__ void pack_all_k(const float* __restrict__ c1w, const float* __restrict__ c2w,
                           const float* __restrict__ c3w, const float* __restrict__ fcw,
                           const float* __restrict__ wih,
                           short* __restrict__ wp1, short* __restrict__ wp2,
                           short* __restrict__ wp3, short* __restrict__ wfcP,
                           short* __restrict__ wihP, int* __restrict__ cnt) {
    int blk = blockIdx.x, tidx = threadIdx.x;
    if (blk < 6272) {                                   // fc: [512][3136]->[j][p*64+oc]
        int g = blk * 256 + tidx;
        int j = g / 3136, kp = g % 3136, p = kp >> 6, oc = kp & 63;
        wfcP[g] = f2bf(fcw[j * 3136 + oc * 49 + p]);
        return;
    }
    blk -= 6272;
    if (blk < 2048) {                                   // wih: drop cols 512..528
        int g = blk * 256 + tidx;
        int r = g >> 9, k = g & 511;
        wihP[g] = f2bf(wih[r * 529 + k]);
        return;
    }
    blk -= 2048;
    if (blk < 32) {                                     // conv1 w
        int g = blk * 256 + tidx;
        int ky = g >> 10, oc = (g >> 5) & 31, k = g & 31, kx = k >> 2, ci = k & 3;
        wp1[g] = f2bf(c1w[((oc * 4 + ci) * 8 + ky) * 8 + kx]);
        return;
    }
    blk -= 32;
    if (blk < 128) {                                    // conv2 w
        int g = blk * 256 + tidx;
        int t = g >> 11, oc = (g >> 5) & 63, ci = g & 31, ky = t >> 2, kx = t & 3;
        wp2[g] = f2bf(c2w[((oc * 32 + ci) * 4 + ky) * 4 + kx]);
        return;
    }
    blk -= 128;
    if (blk < 144) {                                    // conv3 w
        int g = blk * 256 + tidx;
        int tkc = g >> 11, oc = (g >> 5) & 63, c32 = g & 31;
        int t = tkc >> 1, kc = tkc & 1, ky = t / 3, kx = t % 3;
        wp3[g] = f2bf(c3w[((oc * 64 + kc * 32 + c32) * 3 + ky) * 3 + kx]);
        return;
    }
    cnt[tidx] = 0; cnt[256 + tidx] = 0;                 // 512 ints of sync counters
}

// ====== fused conv1+conv2+conv3: x[N,4,84,84] -> (LDS) -> h3_cl[N,49*64] =========
// One block per image.  conv1 runs in 2 passes (oy 0..9 / 10..19), re-staging the
// 44 input rows each pass so xs stays 30 KB -> total LDS 76 KB -> 2 blocks/CU
// (cross-block overlap hides staging).  h1 and h2 never touch HBM.
#define C1_RS 344            // 86 x-slots * 4 ci (entries per row)
__global__ __launch_bounds__(512) void conv123_mfma(
    const float* __restrict__ x,
    const short* __restrict__ wp1, const float* __restrict__ b1v,   // [8][32][32]
    const short* __restrict__ wp2, const float* __restrict__ b2v,   // [16][64][32]
    const short* __restrict__ wp3, const float* __restrict__ b3v,   // [9][2][64][32]
    short* __restrict__ h3) {
    __shared__ short xs[44 * C1_RS];      // 30.3 KB (reused as conv3 out bounce)
    __shared__ short h1s[400 * 40];       // 32 KB   [pix][32 oc +8 pad]
    __shared__ short ob2[96 * 72];        // 13.8 KB [pix][64 oc +8 pad]
    int n = blockIdx.x, tid = threadIdx.x;
    int lane = tid & 63, wid = tid >> 6;
    int lr = lane & 15, kq = lane >> 4;

    // ---- conv1 B-frags + bias (held through both passes) ----
    short8 bfr1[8][2];
#pragma unroll
    for (int ky = 0; ky < 8; ++ky)
#pragma unroll
        for (int nt = 0; nt < 2; ++nt)
            bfr1[ky][nt] = *(const short8*)&wp1[((ky * 32) + nt * 16 + lr) * 32 + kq * 8];
    float b0 = b1v[lr], b1 = b1v[16 + lr];

#pragma unroll
    for (int pass = 0; pass < 2; ++pass) {
        const int iybase = pass ? 39 : -1;           // ry -> iy = iybase + ry
        // ---- stage 44 rows fp32 -> bf16 channels-last ----
        for (int i = tid; i < 44 * 84; i += 512) {
            int ry = i / 84, xi4 = i % 84;
            int ci = xi4 / 21, x4 = xi4 % 21;
            int iy = iybase + ry;
            if (iy < 0) continue;                    // only pass0 ry=0
            float4 v = *(const float4*)(x + (size_t)(n * 4 + ci) * 7056 + iy * 84 + x4 * 4);
            int base = ry * C1_RS + (x4 * 4 + 1) * 4 + ci;
            xs[base] = f2bf(v.x); xs[base + 4] = f2bf(v.y);
            xs[base + 8] = f2bf(v.z); xs[base + 12] = f2bf(v.w);
        }
        for (int i = tid; i < 44 * 4; i += 512)      // zero x-slot 0 (x = -1)
            xs[(i >> 2) * C1_RS + (i & 3)] = 0;
        if (pass == 0)
            for (int i = tid; i < C1_RS; i += 512) xs[i] = 0;   // row iy = -1
        __syncthreads();

        // ---- conv1 for this pass's 200 pixels (13 tiles of 16) ----
        for (int t = wid; t < 13; t += 8) {
            int pl = t * 16 + lr; if (pl > 199) pl = 199;       // clamp (dup reads)
            int p = pass * 200 + pl;
            int oy = p / 20, ox = p % 20;
            f32x4 acc0 = {0.f, 0.f, 0.f, 0.f}, acc1 = {0.f, 0.f, 0.f, 0.f};
#pragma unroll
            for (int ky = 0; ky < 8; ++ky) {
                int ry = oy * 4 + ky - (pass ? 40 : 0);
                short8 af = *(const short8*)&xs[ry * C1_RS + ox * 16 + kq * 8];
                acc0 = MFMA16(af, bfr1[ky][0], acc0);
                acc1 = MFMA16(af, bfr1[ky][1], acc1);
            }
#pragma unroll
            for (int r = 0; r < 4; ++r) {
                int rp = t * 16 + kq * 4 + r;
                if (rp < 200) {                      // mask tail (no LDS overrun)
                    int row = pass * 200 + rp;
                    h1s[row * 40 + lr]      = f2bf(lrelu(acc0[r] + b0));
                    h1s[row * 40 + 16 + lr] = f2bf(lrelu(acc1[r] + b1));
                }
            }
        }
        __syncthreads();                             // xs reads done before restage
    }

    int nt = wid & 3, mh = wid >> 2;
    {   // ---- conv2 from h1s ----
        short8 bfr[16];
#pragma unroll
        for (int t = 0; t < 16; ++t)
            bfr[t] = *(const short8*)&wp2[(t * 64 + nt * 16 + lr) * 32 + kq * 8];
        float bl = b2v[nt * 16 + lr];
        for (int mt = mh * 3; mt < mh * 3 + 3; ++mt) {
            int p = mt * 16 + lr; if (p > 80) p = 80;
            int oy = p / 9, ox = p % 9;
            f32x4 acc = {0.f, 0.f, 0.f, 0.f};
#pragma unroll
            for (int ky = 0; ky < 4; ++ky)
#pragma unroll
                for (int kx = 0; kx < 4; ++kx) {
                    int pix = (oy * 2 + ky) * 20 + ox * 2 + kx;
                    short8 af = *(const short8*)&h1s[pix * 40 + kq * 8];
                    acc = MFMA16(af, bfr[ky * 4 + kx], acc);
                }
            int pm = mt * 16 + kq * 4;
#pragma unroll
            for (int r = 0; r < 4; ++r)
                ob2[(pm + r) * 72 + nt * 16 + lr] = f2bf(lrelu(acc[r] + bl));
        }
    }
    __syncthreads();
    {   // ---- conv3 from ob2 (xs reused as output bounce) ----
        short8 cfr[18];
#pragma unroll
        for (int t = 0; t < 18; ++t)
            cfr[t] = *(const short8*)&wp3[(t * 64 + nt * 16 + lr) * 32 + kq * 8];
        float bl3 = b3v[nt * 16 + lr];
        short* ob3 = xs;
        for (int mt = mh * 2; mt < mh * 2 + 2; ++mt) {
            int p = mt * 16 + lr; if (p > 48) p = 48;
            int oy = p / 7, ox = p % 7;
            f32x4 acc = {0.f, 0.f, 0.f, 0.f};
#pragma unroll
            for (int ky = 0; ky < 3; ++ky)
#pragma unroll
                for (int kx = 0; kx < 3; ++kx) {
                    int pix = (oy + ky) * 9 + ox + kx;
#pragma unroll
                    for (int kc = 0; kc < 2; ++kc) {
                        short8 af = *(const short8*)&ob2[pix * 72 + kc * 32 + kq * 8];
                        acc = MFMA16(af, cfr[(ky * 3 + kx) * 2 + kc], acc);
                    }
                }
            int pm = mt * 16 + kq * 4;
#pragma unroll
            for (int r = 0; r < 4; ++r)
                ob3[(pm + r) * 64 + nt * 16 + lr] = f2bf(lrelu(acc[r] + bl3));
        }
    }
    __syncthreads();
    uint4* dst = (uint4*)(h3 + (size_t)n * 3136);
    for (int i = tid; i < 392; i += 512) dst[i] = ((uint4*)xs)[i];
}

// ========== bf16 GEMM, tile 128x64: C[M,N] = A[M,K] @ B[N,K]^T ==================
// OUT=1: +bias, lrelu, bf16 out.  OUT=2: fp32 out + fused LSTM-gates epilogue.
template <int OUT>
__global__ __launch_bounds__(256) void gemm_bf16(
    const short* __restrict__ A, const short* __restrict__ B,
    const float* __restrict__ bias, void* __restrict__ Cout,
    int M, int N, int K, int ldc,
    const float* __restrict__ reward = nullptr, const int* __restrict__ la = nullptr,
    const float* __restrict__ wih = nullptr, const float* __restrict__ bih = nullptr,
    const float* __restrict__ bhh = nullptr) {
    __shared__ short smem[15360];            // As[2][5120] | Bs[2][2560]
    int m0 = blockIdx.y * 128, n0 = blockIdx.x * 64;
    int tid = threadIdx.x;
    int lane = tid & 63, wid = tid >> 6;
    int wr = wid >> 1, wc = wid & 1;
    int lr = lane & 15, kq = lane >> 4;
    f32x4 acc[4][2];
#pragma unroll
    for (int i = 0; i < 4; ++i)
#pragma unroll
        for (int j = 0; j < 2; ++j) acc[i][j] = (f32x4){0.f, 0.f, 0.f, 0.f};

    int nsteps = K >> 5;
#define STAGE(k0, buf)                                                          \
    {                                                                           \
        short* As = smem + (buf) * 5120;                                        \
        short* Bs = smem + 10240 + (buf) * 2560;                                \
        for (int i = tid; i < 512; i += 256) {                                  \
            int row = i >> 2, c4 = i & 3;                                       \
            *(uint4*)&As[row * 40 + c4 * 8] =                                   \
                *(const uint4*)&A[(size_t)(m0 + row) * K + (k0) + c4 * 8];      \
        }                                                                       \
        {                                                                       \
            int row = tid >> 2, c4 = tid & 3;                                   \
            *(uint4*)&Bs[row * 40 + c4 * 8] =                                   \
                *(const uint4*)&B[(size_t)(n0 + row) * K + (k0) + c4 * 8];      \
        }                                                                       \
    }
    STAGE(0, 0);
    __syncthreads();
    for (int ks = 0; ks < nsteps; ++ks) {
        int buf = ks & 1;
        if (ks + 1 < nsteps) STAGE((ks + 1) * 32, buf ^ 1);
        short* As = smem + buf * 5120;
        short* Bs = smem + 10240 + buf * 2560;
        short8 af[4], bfr[2];
#pragma unroll
        for (int i = 0; i < 4; ++i)
            af[i] = *(const short8*)&As[(wr * 64 + i * 16 + lr) * 40 + kq * 8];
#pragma unroll
        for (int j = 0; j < 2; ++j)
            bfr[j] = *(const short8*)&Bs[(wc * 32 + j * 16 + lr) * 40 + kq * 8];
#pragma unroll
        for (int i = 0; i < 4; ++i)
#pragma unroll
            for (int j = 0; j < 2; ++j)
                acc[i][j] = MFMA16(af[i], bfr[j], acc[i][j]);
        __syncthreads();
    }
#undef STAGE
    if (OUT == 2) {
        float* C = (float*)Cout;
#pragma unroll
        for (int i = 0; i < 4; ++i)
#pragma unroll
            for (int j = 0; j < 2; ++j) {
                int col = n0 + wc * 32 + j * 16 + lr;
                const float* wrow = wih + (size_t)col * 529;
                float base = bih[col] + bhh[col];
                float w512 = wrow[512];
#pragma unroll
                for (int r = 0; r < 4; ++r) {
                    int row = m0 + wr * 64 + i * 16 + kq * 4 + r;
                    C[(size_t)row * ldc + col] =
                        acc[i][j][r] + base + reward[row] * w512 + wrow[513 + la[row]];
                }
            }
    } else {
        short* ob = smem;                             // 128x64 bf16 bounce
#pragma unroll
        for (int i = 0; i < 4; ++i)
#pragma unroll
            for (int j = 0; j < 2; ++j) {
                int col = wc * 32 + j * 16 + lr;
                float bl = bias[n0 + col];
#pragma unroll
                for (int r = 0; r < 4; ++r) {
                    int row = wr * 64 + i * 16 + kq * 4 + r;
                    ob[row * 64 + col] = f2bf(lrelu(acc[i][j][r] + bl));
                }
            }
        __syncthreads();
        short* C = (short*)Cout;
        for (int i = tid; i < 1024; i += 256) {
            int row = i >> 3, c8 = i & 7;
            *(uint4*)&C[(size_t)(m0 + row) * ldc + n0 + c8 * 8] =
                *(uint4*)&ob[row * 64 + c8 * 8];
        }
    }
}

// ---------- LSTM v11 (R11 best, 217us): MFMA recurrence + lean bf16 exchange ----
__global__ __launch_bounds__(512) void lstm16_k(
    const float* __restrict__ gx,        // [N_,1024]
    const float* __restrict__ whh,       // [1024,256] fp32
    const unsigned char* __restrict__ dones,
    const float* __restrict__ hx,        // [2,B_,256]
    float* __restrict__ hs,              // [N_,256]
    unsigned short* __restrict__ hpub,   // [2][B_][256] bf16 ping-pong
    int* __restrict__ cnt) {             // [(grp*2+half)*32]
    const int tid = threadIdx.x;
    const int grp  = blockIdx.x & 7;     // batch group (== XCD), batches grp*4..+3
    const int half = blockIdx.x >> 3;    // hidden half: units half*128..+127
    const int lane = tid & 63, w = tid >> 6;
    const int gt = w >> 1, s2 = w & 1;
    const int lr = lane & 15, kq = lane >> 4;

    __shared__ short hB[16 * 264];       // [batch 16][k 256 +8 pad] bf16
    __shared__ float gate_s[4][128][4];  // [gate][unit][batch]

    // ---- resident A-frags: afr[mi][kt], row = gt*256+half*128+s2*64+mi*16+lr ----
    short8 afr[4][8];
#pragma unroll
    for (int mi = 0; mi < 4; ++mi) {
        int row = gt * 256 + half * 128 + s2 * 64 + mi * 16 + lr;
        const float* wr = whh + (size_t)row * 256;
#pragma unroll
        for (int kt = 0; kt < 8; ++kt) {
            int k0 = kt * 32 + kq * 8;
            float4 a = *(const float4*)(wr + k0);
            float4 b = *(const float4*)(wr + k0 + 4);
            short8 f;
            f[0] = f2bf(a.x); f[1] = f2bf(a.y); f[2] = f2bf(a.z); f[3] = f2bf(a.w);
            f[4] = f2bf(b.x); f[5] = f2bf(b.y); f[6] = f2bf(b.z); f[7] = f2bf(b.w);
            afr[mi][kt] = f;
        }
    }
    {   // pin against rematerialization (R2/R3/R5 lesson)
        int* ap = (int*)afr;
#pragma unroll
        for (int i = 0; i < 128; ++i) asm volatile("" : "+v"(ap[i]));
    }

    // zero unused B rows 4..15 once
    for (int i = tid; i < 12 * 264; i += 512) hB[4 * 264 + i] = 0;

    const int u = tid >> 2, bt = tid & 3;        // pointwise ownership
    const int b = grp * 4 + bt, gu = half * 128 + u;
    float cc = hx[(size_t)B_ * LH_ + b * LH_ + gu];

    // ---- t=1 staging: both halves from hx, dones[0] mask ----
#pragma unroll
    for (int l = 0; l < 2; ++l) {
        int e = tid + l * 512;                   // 0..1023
        int bt2 = e >> 8, k = e & 255;
        int b2 = grp * 4 + bt2;
        float hv = hx[b2 * LH_ + k];
        if (dones[b2]) hv = 0.f;
        hB[bt2 * 264 + k] = f2bf(hv);
    }
    __syncthreads();

    const int mycnt = (grp * 2 + half) * 32, peercnt = (grp * 2 + (half ^ 1)) * 32;
    const int phalf = (half ^ 1) << 7;           // peer's unit base

    for (int t = 1; t <= T_; ++t) {
        const int nb0 = (t - 1) * B_;
        // ---- prefetch gx for pointwise (independent of h) ----
        float gxv[4];
#pragma unroll
        for (int g2 = 0; g2 < 4; ++g2)
            gxv[g2] = gx[(size_t)(nb0 + b) * 1024 + g2 * 256 + gu];

        // ---- wait: peer finished step t-1; stage ONLY peer half ----
        if (t > 1) {
            if (tid == 0) {
                while (__hip_atomic_load(&cnt[peercnt], __ATOMIC_ACQUIRE,
                                         __HIP_MEMORY_SCOPE_AGENT) < t - 1)
                    __builtin_amdgcn_s_sleep(1);
            }
            __syncthreads();
            int bt2 = tid >> 7, pu = tid & 127;      // 4 batches x 128 units
            int b2 = grp * 4 + bt2, pgu = phalf + pu;
            hB[bt2 * 264 + pgu] =
                (short)hpub[((t - 1) & 1) * 8192 + b2 * 256 + pgu];
        }
        __syncthreads();                             // hB complete

        // ---- MFMA: G[64 rows][16 cols(4 used)] per wave ----
        f32x4 acc[4] = {{0.f,0.f,0.f,0.f},{0.f,0.f,0.f,0.f},
                        {0.f,0.f,0.f,0.f},{0.f,0.f,0.f,0.f}};
#pragma unroll
        for (int kt = 0; kt < 8; ++kt) {
            short8 bfr = *(const short8*)&hB[lr * 264 + kt * 32 + kq * 8];
#pragma unroll
            for (int mi = 0; mi < 4; ++mi)
                acc[mi] = MFMA16(afr[mi][kt], bfr, acc[mi]);
        }
        if (lr < 4) {                                // cols 0..3 = real batches
#pragma unroll
            for (int mi = 0; mi < 4; ++mi)
#pragma unroll
                for (int r = 0; r < 4; ++r)
                    gate_s[gt][s2 * 64 + mi * 16 + kq * 4 + r][lr] = acc[mi][r];
        }
        __syncthreads();                             // gates done; hB reads done

        // ---- pointwise: 128 units x 4 batches == 512 threads ----
        {
            bool dn = dones[nb0 + b] != 0;
            float gi = gate_s[0][u][bt] + gxv[0];
            float gf = gate_s[1][u][bt] + gxv[1];
            float gg = gate_s[2][u][bt] + gxv[2];
            float go = gate_s[3][u][bt] + gxv[3];
            float ccv = dn ? 0.f : cc;
            float si = 1.f / (1.f + expf(-gi));
            float sf = 1.f / (1.f + expf(-gf));
            float so = 1.f / (1.f + expf(-go));
            float c2 = sf * ccv + si * tanhf(gg);
            float h2 = so * tanhf(c2);
            cc = c2;
            hs[(size_t)(nb0 + b) * LH_ + gu] = h2;
            if (t < T_) {
                short hm = f2bf(dones[t * B_ + b] ? 0.f : h2);  // pre-masked t+1
                hB[bt * 264 + gu] = hm;                         // own half local
                hpub[(t & 1) * 8192 + b * 256 + gu] = (unsigned short)hm;
            }
        }
        __syncthreads();   // all hpub/hB stores drained before publish
        if (tid == 0)
            __hip_atomic_store(&cnt[mycnt], t, __ATOMIC_RELEASE,
                               __HIP_MEMORY_SCOPE_AGENT);
    }
}

// ---------- heads ----------
__global__ void head_k(const float* __restrict__ hs,
                       const float* __restrict__ aw, const float* __restrict__ ab,
                       const float* __restrict__ cw, const float* __restrict__ cb,
                       float* __restrict__ out) {
    int gid = blockIdx.x * 256 + threadIdx.x;       // N_*17
    if (gid >= N_ * 17) return;
    int n = gid / 17, r = gid % 17;
    const float* f = hs + (size_t)n * 256;
    if (r < 16) {
        const float* w = aw + r * 256;
        float acc = ab[r];
        for (int k = 0; k < 256; ++k) acc = fmaf(f[k], w[k], acc);
        if (isnan(acc)) acc = 1e-12f;
        out[(size_t)n * 16 + r] = acc;
    } else {
        float acc = cb[0];
        for (int k = 0; k < 256; ++k) acc = fmaf(f[k], cw[k], acc);
        out[(size_t)N_ * 16 + n] = acc;
    }
}

extern "C" void kernel_launch(void* const* d_in, const int* in_sizes, int n_in,
                              void* d_out, int out_size, void* d_ws, size_t ws_size,
                              hipStream_t stream) {
    const float* x      = (const float*)d_in[0];
    const int* la       = (const int*)d_in[1];
    const float* reward = (const float*)d_in[2];
    const unsigned char* dones = (const unsigned char*)d_in[3];
    const float* hx     = (const float*)d_in[4];
    const float* c1w = (const float*)d_in[5];  const float* c1b = (const float*)d_in[6];
    const float* c2w = (const float*)d_in[7];  const float* c2b = (const float*)d_in[8];
    const float* c3w = (const float*)d_in[9];  const float* c3b = (const float*)d_in[10];
    const float* fcw = (const float*)d_in[11]; const float* fcb = (const float*)d_in[12];
    const float* wih = (const float*)d_in[13]; const float* whh = (const float*)d_in[14];
    const float* bih = (const float*)d_in[15]; const float* bhh = (const float*)d_in[16];
    const float* aw  = (const float*)d_in[17]; const float* ab  = (const float*)d_in[18];
    const float* cw  = (const float*)d_in[19]; const float* cb  = (const float*)d_in[20];

    char* wsb = (char*)d_ws;
    short* h3   = (short*)(wsb + 92078080);              // 16,056,320 B
    short* hfc  = (short*)(wsb + 108134400);             //  2,621,440
    float* gx   = (float*)(wsb + 110755840);             // 10,485,760
    float* hs   = (float*)(wsb + 121241600);             //  2,621,440
    unsigned short* hpub = (unsigned short*)(wsb + 123863040);  // 32,768
    int*   cnt  = (int*)  (wsb + 123928576);             //      2,048 (16 ctr x 128B)
    short* wp1  = (short*)(wsb + 123932672);             //     16,384
    short* wp2  = (short*)(wsb + 123949056);             //     65,536
    short* wp3  = (short*)(wsb + 124014592);             //     73,728
    short* wfcP = (short*)(wsb + 124088320);             //  3,211,264
    short* wihP = (short*)(wsb + 127299584);             //  1,048,576

    pack_all_k<<<8625, 256, 0, stream>>>(c1w, c2w, c3w, fcw, wih,
                                         wp1, wp2, wp3, wfcP, wihP, cnt);

    conv123_mfma<<<2560, 512, 0, stream>>>(x, wp1, c1b, wp2, c2b, wp3, c3b, h3);

    gemm_bf16<1><<<dim3(8, 20), 256, 0, stream>>>(h3, wfcP, fcb, hfc,
                                                  2560, 512, 3136, 512);
    gemm_bf16<2><<<dim3(16, 20), 256, 0, stream>>>(hfc, wihP, nullptr, gx,
                                                   2560, 1024, 512, 1024,
                                                   reward, la, wih, bih, bhh);

    lstm16_k<<<16, 512, 0, stream>>>(gx, whh, dones, hx, hs, hpub, cnt);
    head_k<<<170, 256, 0, stream>>>(hs, aw, ab, cw, cb, (float*)d_out);
}

// Round 13
// 481.964 us; speedup vs baseline: 1.7152x; 1.0076x over previous
//
#include <hip/hip_runtime.h>
#include <math.h>

#define T_ 80
#define B_ 32
#define N_ 2560            // T_*B_
#define LH_ 256

typedef __attribute__((ext_vector_type(8))) short short8;
typedef __attribute__((ext_vector_type(4))) float f32x4;
#define MFMA16(a, b, c) __builtin_amdgcn_mfma_f32_16x16x32_bf16((a), (b), (c), 0, 0, 0)

__device__ __forceinline__ float lrelu(float v) { return v > 0.f ? v : 0.01f * v; }
__device__ __forceinline__ short f2bf(float f) {        // RNE float->bf16 bits
    unsigned u = __float_as_uint(f);
    return (short)((u + 0x7fffu + ((u >> 16) & 1u)) >> 16);
}

// ========== fused weight-pack + flag-zero (one kernel) ==========================
// fc part: one block per fc row, LDS transpose -> coalesced read AND write
// (R12 version gathered fcw at stride 49 across 6272 blocks).
__global__ void pack_all_k(const float* __restrict__ c1w, const float* __restrict__ c2w,
                           const float* __restrict__ c3w, const float* __restrict__ fcw,
                           const float* __restrict__ wih,
                           short* __restrict__ wp1, short* __restrict__ wp2,
                           short* __restrict__ wp3, short* __restrict__ wfcP,
                           short* __restrict__ wihP, int* __restrict__ cnt) {
    __shared__ short rowb[3136];
    int blk = blockIdx.x, tidx = threadIdx.x;
    if (blk < 512) {                                    // fc row j: [3136] -> [p*64+oc]
        int j = blk;
        for (int i = tidx; i < 3136; i += 256) rowb[i] = f2bf(fcw[j * 3136 + i]);
        __syncthreads();
        for (int i = tidx; i < 3136; i += 256) {
            int p = i >> 6, oc = i & 63;
            wfcP[j * 3136 + i] = rowb[oc * 49 + p];
        }
        return;
    }
    blk -= 512;
    if (blk < 2048) {                                   // wih: drop cols 512..528
        int g = blk * 256 + tidx;
        int r = g >> 9, k = g & 511;
        wihP[g] = f2bf(wih[r * 529 + k]);
        return;
    }
    blk -= 2048;
    if (blk < 32) {                                     // conv1 w
        int g = blk * 256 + tidx;
        int ky = g >> 10, oc = (g >> 5) & 31, k = g & 31, kx = k >> 2, ci = k & 3;
        wp1[g] = f2bf(c1w[((oc * 4 + ci) * 8 + ky) * 8 + kx]);
        return;
    }
    blk -= 32;
    if (blk < 128) {                                    // conv2 w
        int g = blk * 256 + tidx;
        int t = g >> 11, oc = (g >> 5) & 63, ci = g & 31, ky = t >> 2, kx = t & 3;
        wp2[g] = f2bf(c2w[((oc * 32 + ci) * 4 + ky) * 4 + kx]);
        return;
    }
    blk -= 128;
    if (blk < 144) {                                    // conv3 w
        int g = blk * 256 + tidx;
        int tkc = g >> 11, oc = (g >> 5) & 63, c32 = g & 31;
        int t = tkc >> 1, kc = tkc & 1, ky = t / 3, kx = t % 3;
        wp3[g] = f2bf(c3w[((oc * 64 + kc * 32 + c32) * 3 + ky) * 3 + kx]);
        return;
    }
    cnt[tidx] = 0; cnt[256 + tidx] = 0;                 // 512 ints of sync counters
}

// ====== fused conv1+conv2+conv3: x[N,4,84,84] -> (LDS) -> h3_cl[N,49*64] =========
#define C1_RS 344            // 86 x-slots * 4 ci (entries per row)
__global__ __launch_bounds__(512) void conv123_mfma(
    const float* __restrict__ x,
    const short* __restrict__ wp1, const float* __restrict__ b1v,   // [8][32][32]
    const short* __restrict__ wp2, const float* __restrict__ b2v,   // [16][64][32]
    const short* __restrict__ wp3, const float* __restrict__ b3v,   // [9][2][64][32]
    short* __restrict__ h3) {
    __shared__ short xs[44 * C1_RS];      // 30.3 KB (reused as conv3 out bounce)
    __shared__ short h1s[400 * 40];       // 32 KB   [pix][32 oc +8 pad]
    __shared__ short ob2[96 * 72];        // 13.8 KB [pix][64 oc +8 pad]
    int n = blockIdx.x, tid = threadIdx.x;
    int lane = tid & 63, wid = tid >> 6;
    int lr = lane & 15, kq = lane >> 4;

    // ---- conv1 B-frags + bias (held through both passes) ----
    short8 bfr1[8][2];
#pragma unroll
    for (int ky = 0; ky < 8; ++ky)
#pragma unroll
        for (int nt = 0; nt < 2; ++nt)
            bfr1[ky][nt] = *(const short8*)&wp1[((ky * 32) + nt * 16 + lr) * 32 + kq * 8];
    float b0 = b1v[lr], b1 = b1v[16 + lr];

#pragma unroll
    for (int pass = 0; pass < 2; ++pass) {
        const int iybase = pass ? 39 : -1;           // ry -> iy = iybase + ry
        for (int i = tid; i < 44 * 84; i += 512) {
            int ry = i / 84, xi4 = i % 84;
            int ci = xi4 / 21, x4 = xi4 % 21;
            int iy = iybase + ry;
            if (iy < 0) continue;                    // only pass0 ry=0
            float4 v = *(const float4*)(x + (size_t)(n * 4 + ci) * 7056 + iy * 84 + x4 * 4);
            int base = ry * C1_RS + (x4 * 4 + 1) * 4 + ci;
            xs[base] = f2bf(v.x); xs[base + 4] = f2bf(v.y);
            xs[base + 8] = f2bf(v.z); xs[base + 12] = f2bf(v.w);
        }
        for (int i = tid; i < 44 * 4; i += 512)      // zero x-slot 0 (x = -1)
            xs[(i >> 2) * C1_RS + (i & 3)] = 0;
        if (pass == 0)
            for (int i = tid; i < C1_RS; i += 512) xs[i] = 0;   // row iy = -1
        __syncthreads();

        for (int t = wid; t < 13; t += 8) {
            int pl = t * 16 + lr; if (pl > 199) pl = 199;       // clamp (dup reads)
            int p = pass * 200 + pl;
            int oy = p / 20, ox = p % 20;
            f32x4 acc0 = {0.f, 0.f, 0.f, 0.f}, acc1 = {0.f, 0.f, 0.f, 0.f};
#pragma unroll
            for (int ky = 0; ky < 8; ++ky) {
                int ry = oy * 4 + ky - (pass ? 40 : 0);
                short8 af = *(const short8*)&xs[ry * C1_RS + ox * 16 + kq * 8];
                acc0 = MFMA16(af, bfr1[ky][0], acc0);
                acc1 = MFMA16(af, bfr1[ky][1], acc1);
            }
#pragma unroll
            for (int r = 0; r < 4; ++r) {
                int rp = t * 16 + kq * 4 + r;
                if (rp < 200) {
                    int row = pass * 200 + rp;
                    h1s[row * 40 + lr]      = f2bf(lrelu(acc0[r] + b0));
                    h1s[row * 40 + 16 + lr] = f2bf(lrelu(acc1[r] + b1));
                }
            }
        }
        __syncthreads();                             // xs reads done before restage
    }

    int nt = wid & 3, mh = wid >> 2;
    {   // ---- conv2 from h1s ----
        short8 bfr[16];
#pragma unroll
        for (int t = 0; t < 16; ++t)
            bfr[t] = *(const short8*)&wp2[(t * 64 + nt * 16 + lr) * 32 + kq * 8];
        float bl = b2v[nt * 16 + lr];
        for (int mt = mh * 3; mt < mh * 3 + 3; ++mt) {
            int p = mt * 16 + lr; if (p > 80) p = 80;
            int oy = p / 9, ox = p % 9;
            f32x4 acc = {0.f, 0.f, 0.f, 0.f};
#pragma unroll
            for (int ky = 0; ky < 4; ++ky)
#pragma unroll
                for (int kx = 0; kx < 4; ++kx) {
                    int pix = (oy * 2 + ky) * 20 + ox * 2 + kx;
                    short8 af = *(const short8*)&h1s[pix * 40 + kq * 8];
                    acc = MFMA16(af, bfr[ky * 4 + kx], acc);
                }
            int pm = mt * 16 + kq * 4;
#pragma unroll
            for (int r = 0; r < 4; ++r)
                ob2[(pm + r) * 72 + nt * 16 + lr] = f2bf(lrelu(acc[r] + bl));
        }
    }
    __syncthreads();
    {   // ---- conv3 from ob2 (xs reused as output bounce) ----
        short8 cfr[18];
#pragma unroll
        for (int t = 0; t < 18; ++t)
            cfr[t] = *(const short8*)&wp3[(t * 64 + nt * 16 + lr) * 32 + kq * 8];
        float bl3 = b3v[nt * 16 + lr];
        short* ob3 = xs;
        for (int mt = mh * 2; mt < mh * 2 + 2; ++mt) {
            int p = mt * 16 + lr; if (p > 48) p = 48;
            int oy = p / 7, ox = p % 7;
            f32x4 acc = {0.f, 0.f, 0.f, 0.f};
#pragma unroll
            for (int ky = 0; ky < 3; ++ky)
#pragma unroll
                for (int kx = 0; kx < 3; ++kx) {
                    int pix = (oy + ky) * 9 + ox + kx;
#pragma unroll
                    for (int kc = 0; kc < 2; ++kc) {
                        short8 af = *(const short8*)&ob2[pix * 72 + kc * 32 + kq * 8];
                        acc = MFMA16(af, cfr[(ky * 3 + kx) * 2 + kc], acc);
                    }
                }
            int pm = mt * 16 + kq * 4;
#pragma unroll
            for (int r = 0; r < 4; ++r)
                ob3[(pm + r) * 64 + nt * 16 + lr] = f2bf(lrelu(acc[r] + bl3));
        }
    }
    __syncthreads();
    uint4* dst = (uint4*)(h3 + (size_t)n * 3136);
    for (int i = tid; i < 392; i += 512) dst[i] = ((uint4*)xs)[i];
}

// ========== bf16 GEMM, tile 128x64: C[M,N] = A[M,K] @ B[N,K]^T ==================
// OUT=1: +bias, lrelu, bf16 out.  OUT=2: fp32 out + fused LSTM-gates epilogue.
template <int OUT>
__global__ __launch_bounds__(256) void gemm_bf16(
    const short* __restrict__ A, const short* __restrict__ B,
    const float* __restrict__ bias, void* __restrict__ Cout,
    int M, int N, int K, int ldc,
    const float* __restrict__ reward = nullptr, const int* __restrict__ la = nullptr,
    const float* __restrict__ wih = nullptr, const float* __restrict__ bih = nullptr,
    const float* __restrict__ bhh = nullptr) {
    __shared__ short smem[15360];            // As[2][5120] | Bs[2][2560]
    int m0 = blockIdx.y * 128, n0 = blockIdx.x * 64;
    int tid = threadIdx.x;
    int lane = tid & 63, wid = tid >> 6;
    int wr = wid >> 1, wc = wid & 1;
    int lr = lane & 15, kq = lane >> 4;
    f32x4 acc[4][2];
#pragma unroll
    for (int i = 0; i < 4; ++i)
#pragma unroll
        for (int j = 0; j < 2; ++j) acc[i][j] = (f32x4){0.f, 0.f, 0.f, 0.f};

    int nsteps = K >> 5;
#define STAGE(k0, buf)                                                          \
    {                                                                           \
        short* As = smem + (buf) * 5120;                                        \
        short* Bs = smem + 10240 + (buf) * 2560;                                \
        for (int i = tid; i < 512; i += 256) {                                  \
            int row = i >> 2, c4 = i & 3;                                       \
            *(uint4*)&As[row * 40 + c4 * 8] =                                   \
                *(const uint4*)&A[(size_t)(m0 + row) * K + (k0) + c4 * 8];      \
        }                                                                       \
        {                                                                       \
            int row = tid >> 2, c4 = tid & 3;                                   \
            *(uint4*)&Bs[row * 40 + c4 * 8] =                                   \
                *(const uint4*)&B[(size_t)(n0 + row) * K + (k0) + c4 * 8];      \
        }                                                                       \
    }
    STAGE(0, 0);
    __syncthreads();
    for (int ks = 0; ks < nsteps; ++ks) {
        int buf = ks & 1;
        if (ks + 1 < nsteps) STAGE((ks + 1) * 32, buf ^ 1);
        short* As = smem + buf * 5120;
        short* Bs = smem + 10240 + buf * 2560;
        short8 af[4], bfr[2];
#pragma unroll
        for (int i = 0; i < 4; ++i)
            af[i] = *(const short8*)&As[(wr * 64 + i * 16 + lr) * 40 + kq * 8];
#pragma unroll
        for (int j = 0; j < 2; ++j)
            bfr[j] = *(const short8*)&Bs[(wc * 32 + j * 16 + lr) * 40 + kq * 8];
#pragma unroll
        for (int i = 0; i < 4; ++i)
#pragma unroll
            for (int j = 0; j < 2; ++j)
                acc[i][j] = MFMA16(af[i], bfr[j], acc[i][j]);
        __syncthreads();
    }
#undef STAGE
    if (OUT == 2) {
        float* C = (float*)Cout;
#pragma unroll
        for (int i = 0; i < 4; ++i)
#pragma unroll
            for (int j = 0; j < 2; ++j) {
                int col = n0 + wc * 32 + j * 16 + lr;
                const float* wrow = wih + (size_t)col * 529;
                float base = bih[col] + bhh[col];
                float w512 = wrow[512];
#pragma unroll
                for (int r = 0; r < 4; ++r) {
                    int row = m0 + wr * 64 + i * 16 + kq * 4 + r;
                    C[(size_t)row * ldc + col] =
                        acc[i][j][r] + base + reward[row] * w512 + wrow[513 + la[row]];
                }
            }
    } else {
        short* ob = smem;                             // 128x64 bf16 bounce
#pragma unroll
        for (int i = 0; i < 4; ++i)
#pragma unroll
            for (int j = 0; j < 2; ++j) {
                int col = wc * 32 + j * 16 + lr;
                float bl = bias[n0 + col];
#pragma unroll
                for (int r = 0; r < 4; ++r) {
                    int row = wr * 64 + i * 16 + kq * 4 + r;
                    ob[row * 64 + col] = f2bf(lrelu(acc[i][j][r] + bl));
                }
            }
        __syncthreads();
        short* C = (short*)Cout;
        for (int i = tid; i < 1024; i += 256) {
            int row = i >> 3, c8 = i & 7;
            *(uint4*)&C[(size_t)(m0 + row) * ldc + n0 + c8 * 8] =
                *(uint4*)&ob[row * 64 + c8 * 8];
        }
    }
}

// ---------- LSTM v12: R11 structure + lean spin ---------------------------------
// Spin change: tid0 polls with RELAXED loads (no per-iteration L1 invalidate, no
// s_sleep) + ONE acquire fence on exit; barrier fans out.  (R8's regression was
// the ALL-THREAD spin -- tid0-relaxed was never tested.)  hpub published before
// the hs/hB stores so the release chain starts earlier.
__global__ __launch_bounds__(512) void lstm16_k(
    const float* __restrict__ gx,        // [N_,1024]
    const float* __restrict__ whh,       // [1024,256] fp32
    const unsigned char* __restrict__ dones,
    const float* __restrict__ hx,        // [2,B_,256]
    float* __restrict__ hs,              // [N_,256]
    unsigned short* __restrict__ hpub,   // [2][B_][256] bf16 ping-pong
    int* __restrict__ cnt) {             // [(grp*2+half)*32]
    const int tid = threadIdx.x;
    const int grp  = blockIdx.x & 7;     // batch group (== XCD), batches grp*4..+3
    const int half = blockIdx.x >> 3;    // hidden half: units half*128..+127
    const int lane = tid & 63, w = tid >> 6;
    const int gt = w >> 1, s2 = w & 1;
    const int lr = lane & 15, kq = lane >> 4;

    __shared__ short hB[16 * 264];       // [batch 16][k 256 +8 pad] bf16
    __shared__ float gate_s[4][128][4];  // [gate][unit][batch]

    // ---- resident A-frags: afr[mi][kt], row = gt*256+half*128+s2*64+mi*16+lr ----
    short8 afr[4][8];
#pragma unroll
    for (int mi = 0; mi < 4; ++mi) {
        int row = gt * 256 + half * 128 + s2 * 64 + mi * 16 + lr;
        const float* wr = whh + (size_t)row * 256;
#pragma unroll
        for (int kt = 0; kt < 8; ++kt) {
            int k0 = kt * 32 + kq * 8;
            float4 a = *(const float4*)(wr + k0);
            float4 b = *(const float4*)(wr + k0 + 4);
            short8 f;
            f[0] = f2bf(a.x); f[1] = f2bf(a.y); f[2] = f2bf(a.z); f[3] = f2bf(a.w);
            f[4] = f2bf(b.x); f[5] = f2bf(b.y); f[6] = f2bf(b.z); f[7] = f2bf(b.w);
            afr[mi][kt] = f;
        }
    }
    {   // pin against rematerialization (R2/R3/R5 lesson)
        int* ap = (int*)afr;
#pragma unroll
        for (int i = 0; i < 128; ++i) asm volatile("" : "+v"(ap[i]));
    }

    // zero unused B rows 4..15 once
    for (int i = tid; i < 12 * 264; i += 512) hB[4 * 264 + i] = 0;

    const int u = tid >> 2, bt = tid & 3;        // pointwise ownership
    const int b = grp * 4 + bt, gu = half * 128 + u;
    float cc = hx[(size_t)B_ * LH_ + b * LH_ + gu];

    // ---- t=1 staging: both halves from hx, dones[0] mask ----
#pragma unroll
    for (int l = 0; l < 2; ++l) {
        int e = tid + l * 512;                   // 0..1023
        int bt2 = e >> 8, k = e & 255;
        int b2 = grp * 4 + bt2;
        float hv = hx[b2 * LH_ + k];
        if (dones[b2]) hv = 0.f;
        hB[bt2 * 264 + k] = f2bf(hv);
    }
    __syncthreads();

    const int mycnt = (grp * 2 + half) * 32, peercnt = (grp * 2 + (half ^ 1)) * 32;
    const int phalf = (half ^ 1) << 7;           // peer's unit base

    for (int t = 1; t <= T_; ++t) {
        const int nb0 = (t - 1) * B_;
        // ---- prefetch gx for pointwise (independent of h, overlaps spin) ----
        float gxv[4];
#pragma unroll
        for (int g2 = 0; g2 < 4; ++g2)
            gxv[g2] = gx[(size_t)(nb0 + b) * 1024 + g2 * 256 + gu];

        // ---- wait: peer finished step t-1; stage ONLY peer half ----
        if (t > 1) {
            if (tid == 0) {
                while (__hip_atomic_load(&cnt[peercnt], __ATOMIC_RELAXED,
                                         __HIP_MEMORY_SCOPE_AGENT) < t - 1) {}
                __builtin_amdgcn_fence(__ATOMIC_ACQUIRE, "agent");  // one L1 inv
            }
            __syncthreads();
            int bt2 = tid >> 7, pu = tid & 127;      // 4 batches x 128 units
            int b2 = grp * 4 + bt2, pgu = phalf + pu;
            hB[bt2 * 264 + pgu] =
                (short)hpub[((t - 1) & 1) * 8192 + b2 * 256 + pgu];
        }
        __syncthreads();                             // hB complete

        // ---- MFMA: G[64 rows][16 cols(4 used)] per wave ----
        f32x4 acc[4] = {{0.f,0.f,0.f,0.f},{0.f,0.f,0.f,0.f},
                        {0.f,0.f,0.f,0.f},{0.f,0.f,0.f,0.f}};
#pragma unroll
        for (int kt = 0; kt < 8; ++kt) {
            short8 bfr = *(const short8*)&hB[lr * 264 + kt * 32 + kq * 8];
#pragma unroll
            for (int mi = 0; mi < 4; ++mi)
                acc[mi] = MFMA16(afr[mi][kt], bfr, acc[mi]);
        }
        if (lr < 4) {                                // cols 0..3 = real batches
#pragma unroll
            for (int mi = 0; mi < 4; ++mi)
#pragma unroll
                for (int r = 0; r < 4; ++r)
                    gate_s[gt][s2 * 64 + mi * 16 + kq * 4 + r][lr] = acc[mi][r];
        }
        __syncthreads();                             // gates done; hB reads done

        // ---- pointwise: 128 units x 4 batches == 512 threads ----
        {
            bool dn = dones[nb0 + b] != 0;
            float gi = gate_s[0][u][bt] + gxv[0];
            float gf = gate_s[1][u][bt] + gxv[1];
            float gg = gate_s[2][u][bt] + gxv[2];
            float go = gate_s[3][u][bt] + gxv[3];
            float ccv = dn ? 0.f : cc;
            float si = 1.f / (1.f + expf(-gi));
            float sf = 1.f / (1.f + expf(-gf));
            float so = 1.f / (1.f + expf(-go));
            float c2 = sf * ccv + si * tanhf(gg);
            float h2 = so * tanhf(c2);
            cc = c2;
            if (t < T_) {
                short hm = f2bf(dones[t * B_ + b] ? 0.f : h2);  // pre-masked t+1
                hpub[(t & 1) * 8192 + b * 256 + gu] = (unsigned short)hm;  // first
                hB[bt * 264 + gu] = hm;                         // own half local
            }
            hs[(size_t)(nb0 + b) * LH_ + gu] = h2;
        }
        __syncthreads();   // all hpub/hB stores drained before publish
        if (tid == 0)
            __hip_atomic_store(&cnt[mycnt], t, __ATOMIC_RELEASE,
                               __HIP_MEMORY_SCOPE_AGENT);
    }
}

// ---------- heads ----------
__global__ void head_k(const float* __restrict__ hs,
                       const float* __restrict__ aw, const float* __restrict__ ab,
                       const float* __restrict__ cw, const float* __restrict__ cb,
                       float* __restrict__ out) {
    int gid = blockIdx.x * 256 + threadIdx.x;       // N_*17
    if (gid >= N_ * 17) return;
    int n = gid / 17, r = gid % 17;
    const float* f = hs + (size_t)n * 256;
    if (r < 16) {
        const float* w = aw + r * 256;
        float acc = ab[r];
        for (int k = 0; k < 256; ++k) acc = fmaf(f[k], w[k], acc);
        if (isnan(acc)) acc = 1e-12f;
        out[(size_t)n * 16 + r] = acc;
    } else {
        float acc = cb[0];
        for (int k = 0; k < 256; ++k) acc = fmaf(f[k], cw[k], acc);
        out[(size_t)N_ * 16 + n] = acc;
    }
}

extern "C" void kernel_launch(void* const* d_in, const int* in_sizes, int n_in,
                              void* d_out, int out_size, void* d_ws, size_t ws_size,
                              hipStream_t stream) {
    const float* x      = (const float*)d_in[0];
    const int* la       = (const int*)d_in[1];
    const float* reward = (const float*)d_in[2];
    const unsigned char* dones = (const unsigned char*)d_in[3];
    const float* hx     = (const float*)d_in[4];
    const float* c1w = (const float*)d_in[5];  const float* c1b = (const float*)d_in[6];
    const float* c2w = (const float*)d_in[7];  const float* c2b = (const float*)d_in[8];
    const float* c3w = (const float*)d_in[9];  const float* c3b = (const float*)d_in[10];
    const float* fcw = (const float*)d_in[11]; const float* fcb = (const float*)d_in[12];
    const float* wih = (const float*)d_in[13]; const float* whh = (const float*)d_in[14];
    const float* bih = (const float*)d_in[15]; const float* bhh = (const float*)d_in[16];
    const float* aw  = (const float*)d_in[17]; const float* ab  = (const float*)d_in[18];
    const float* cw  = (const float*)d_in[19]; const float* cb  = (const float*)d_in[20];

    char* wsb = (char*)d_ws;
    short* h3   = (short*)(wsb + 92078080);              // 16,056,320 B
    short* hfc  = (short*)(wsb + 108134400);             //  2,621,440
    float* gx   = (float*)(wsb + 110755840);             // 10,485,760
    float* hs   = (float*)(wsb + 121241600);             //  2,621,440
    unsigned short* hpub = (unsigned short*)(wsb + 123863040);  // 32,768
    int*   cnt  = (int*)  (wsb + 123928576);             //      2,048 (16 ctr x 128B)
    short* wp1  = (short*)(wsb + 123932672);             //     16,384
    short* wp2  = (short*)(wsb + 123949056);             //     65,536
    short* wp3  = (short*)(wsb + 124014592);             //     73,728
    short* wfcP = (short*)(wsb + 124088320);             //  3,211,264
    short* wihP = (short*)(wsb + 127299584);             //  1,048,576

    pack_all_k<<<2865, 256, 0, stream>>>(c1w, c2w, c3w, fcw, wih,
                                         wp1, wp2, wp3, wfcP, wihP, cnt);

    conv123_mfma<<<2560, 512, 0, stream>>>(x, wp1, c1b, wp2, c2b, wp3, c3b, h3);

    gemm_bf16<1><<<dim3(8, 20), 256, 0, stream>>>(h3, wfcP, fcb, hfc,
                                                  2560, 512, 3136, 512);
    gemm_bf16<2><<<dim3(16, 20), 256, 0, stream>>>(hfc, wihP, nullptr, gx,
                                                   2560, 1024, 512, 1024,
                                                   reward, la, wih, bih, bhh);

    lstm16_k<<<16, 512, 0, stream>>>(gx, whh, dones, hx, hs, hpub, cnt);
    head_k<<<170, 256, 0, stream>>>(hs, aw, ab, cw, cb, (float*)d_out);
}

// Round 14
// 468.025 us; speedup vs baseline: 1.7663x; 1.0298x over previous
//
#include <hip/hip_runtime.h>
#include <math.h>

#define T_ 80
#define B_ 32
#define N_ 2560            // T_*B_
#define LH_ 256

typedef __attribute__((ext_vector_type(8))) short short8;
typedef __attribute__((ext_vector_type(4))) float f32x4;
#define MFMA16(a, b, c) __builtin_amdgcn_mfma_f32_16x16x32_bf16((a), (b), (c), 0, 0, 0)

__device__ __forceinline__ float lrelu(float v) { return v > 0.f ? v : 0.01f * v; }
__device__ __forceinline__ short f2bf(float f) {        // RNE float->bf16 bits
    unsigned u = __float_as_uint(f);
    return (short)((u + 0x7fffu + ((u >> 16) & 1u)) >> 16);
}

// ========== fused weight-pack (one kernel) ======================================
__global__ void pack_all_k(const float* __restrict__ c1w, const float* __restrict__ c2w,
                           const float* __restrict__ c3w, const float* __restrict__ fcw,
                           const float* __restrict__ wih,
                           short* __restrict__ wp1, short* __restrict__ wp2,
                           short* __restrict__ wp3, short* __restrict__ wfcP,
                           short* __restrict__ wihP) {
    __shared__ short rowb[3136];
    int blk = blockIdx.x, tidx = threadIdx.x;
    if (blk < 512) {                                    // fc row j: [3136] -> [p*64+oc]
        int j = blk;
        for (int i = tidx; i < 3136; i += 256) rowb[i] = f2bf(fcw[j * 3136 + i]);
        __syncthreads();
        for (int i = tidx; i < 3136; i += 256) {
            int p = i >> 6, oc = i & 63;
            wfcP[j * 3136 + i] = rowb[oc * 49 + p];
        }
        return;
    }
    blk -= 512;
    if (blk < 2048) {                                   // wih: drop cols 512..528
        int g = blk * 256 + tidx;
        int r = g >> 9, k = g & 511;
        wihP[g] = f2bf(wih[r * 529 + k]);
        return;
    }
    blk -= 2048;
    if (blk < 32) {                                     // conv1 w
        int g = blk * 256 + tidx;
        int ky = g >> 10, oc = (g >> 5) & 31, k = g & 31, kx = k >> 2, ci = k & 3;
        wp1[g] = f2bf(c1w[((oc * 4 + ci) * 8 + ky) * 8 + kx]);
        return;
    }
    blk -= 32;
    if (blk < 128) {                                    // conv2 w
        int g = blk * 256 + tidx;
        int t = g >> 11, oc = (g >> 5) & 63, ci = g & 31, ky = t >> 2, kx = t & 3;
        wp2[g] = f2bf(c2w[((oc * 32 + ci) * 4 + ky) * 4 + kx]);
        return;
    }
    blk -= 128;
    {                                                   // conv3 w (144 blocks)
        int g = blk * 256 + tidx;
        int tkc = g >> 11, oc = (g >> 5) & 63, c32 = g & 31;
        int t = tkc >> 1, kc = tkc & 1, ky = t / 3, kx = t % 3;
        wp3[g] = f2bf(c3w[((oc * 64 + kc * 32 + c32) * 3 + ky) * 3 + kx]);
    }
}

// ====== fused conv1+conv2+conv3: x[N,4,84,84] -> (LDS) -> h3_cl[N,49*64] =========
#define C1_RS 344            // 86 x-slots * 4 ci (entries per row)
__global__ __launch_bounds__(512) void conv123_mfma(
    const float* __restrict__ x,
    const short* __restrict__ wp1, const float* __restrict__ b1v,   // [8][32][32]
    const short* __restrict__ wp2, const float* __restrict__ b2v,   // [16][64][32]
    const short* __restrict__ wp3, const float* __restrict__ b3v,   // [9][2][64][32]
    short* __restrict__ h3) {
    __shared__ short xs[44 * C1_RS];      // 30.3 KB (reused as conv3 out bounce)
    __shared__ short h1s[400 * 40];       // 32 KB   [pix][32 oc +8 pad]
    __shared__ short ob2[96 * 72];        // 13.8 KB [pix][64 oc +8 pad]
    int n = blockIdx.x, tid = threadIdx.x;
    int lane = tid & 63, wid = tid >> 6;
    int lr = lane & 15, kq = lane >> 4;

    short8 bfr1[8][2];
#pragma unroll
    for (int ky = 0; ky < 8; ++ky)
#pragma unroll
        for (int nt = 0; nt < 2; ++nt)
            bfr1[ky][nt] = *(const short8*)&wp1[((ky * 32) + nt * 16 + lr) * 32 + kq * 8];
    float b0 = b1v[lr], b1 = b1v[16 + lr];

#pragma unroll
    for (int pass = 0; pass < 2; ++pass) {
        const int iybase = pass ? 39 : -1;           // ry -> iy = iybase + ry
        for (int i = tid; i < 44 * 84; i += 512) {
            int ry = i / 84, xi4 = i % 84;
            int ci = xi4 / 21, x4 = xi4 % 21;
            int iy = iybase + ry;
            if (iy < 0) continue;                    // only pass0 ry=0
            float4 v = *(const float4*)(x + (size_t)(n * 4 + ci) * 7056 + iy * 84 + x4 * 4);
            int base = ry * C1_RS + (x4 * 4 + 1) * 4 + ci;
            xs[base] = f2bf(v.x); xs[base + 4] = f2bf(v.y);
            xs[base + 8] = f2bf(v.z); xs[base + 12] = f2bf(v.w);
        }
        for (int i = tid; i < 44 * 4; i += 512)      // zero x-slot 0 (x = -1)
            xs[(i >> 2) * C1_RS + (i & 3)] = 0;
        if (pass == 0)
            for (int i = tid; i < C1_RS; i += 512) xs[i] = 0;   // row iy = -1
        __syncthreads();

        for (int t = wid; t < 13; t += 8) {
            int pl = t * 16 + lr; if (pl > 199) pl = 199;       // clamp (dup reads)
            int p = pass * 200 + pl;
            int oy = p / 20, ox = p % 20;
            f32x4 acc0 = {0.f, 0.f, 0.f, 0.f}, acc1 = {0.f, 0.f, 0.f, 0.f};
#pragma unroll
            for (int ky = 0; ky < 8; ++ky) {
                int ry = oy * 4 + ky - (pass ? 40 : 0);
                short8 af = *(const short8*)&xs[ry * C1_RS + ox * 16 + kq * 8];
                acc0 = MFMA16(af, bfr1[ky][0], acc0);
                acc1 = MFMA16(af, bfr1[ky][1], acc1);
            }
#pragma unroll
            for (int r = 0; r < 4; ++r) {
                int rp = t * 16 + kq * 4 + r;
                if (rp < 200) {
                    int row = pass * 200 + rp;
                    h1s[row * 40 + lr]      = f2bf(lrelu(acc0[r] + b0));
                    h1s[row * 40 + 16 + lr] = f2bf(lrelu(acc1[r] + b1));
                }
            }
        }
        __syncthreads();                             // xs reads done before restage
    }

    int nt = wid & 3, mh = wid >> 2;
    {   // ---- conv2 from h1s ----
        short8 bfr[16];
#pragma unroll
        for (int t = 0; t < 16; ++t)
            bfr[t] = *(const short8*)&wp2[(t * 64 + nt * 16 + lr) * 32 + kq * 8];
        float bl = b2v[nt * 16 + lr];
        for (int mt = mh * 3; mt < mh * 3 + 3; ++mt) {
            int p = mt * 16 + lr; if (p > 80) p = 80;
            int oy = p / 9, ox = p % 9;
            f32x4 acc = {0.f, 0.f, 0.f, 0.f};
#pragma unroll
            for (int ky = 0; ky < 4; ++ky)
#pragma unroll
                for (int kx = 0; kx < 4; ++kx) {
                    int pix = (oy * 2 + ky) * 20 + ox * 2 + kx;
                    short8 af = *(const short8*)&h1s[pix * 40 + kq * 8];
                    acc = MFMA16(af, bfr[ky * 4 + kx], acc);
                }
            int pm = mt * 16 + kq * 4;
#pragma unroll
            for (int r = 0; r < 4; ++r)
                ob2[(pm + r) * 72 + nt * 16 + lr] = f2bf(lrelu(acc[r] + bl));
        }
    }
    __syncthreads();
    {   // ---- conv3 from ob2 (xs reused as output bounce) ----
        short8 cfr[18];
#pragma unroll
        for (int t = 0; t < 18; ++t)
            cfr[t] = *(const short8*)&wp3[(t * 64 + nt * 16 + lr) * 32 + kq * 8];
        float bl3 = b3v[nt * 16 + lr];
        short* ob3 = xs;
        for (int mt = mh * 2; mt < mh * 2 + 2; ++mt) {
            int p = mt * 16 + lr; if (p > 48) p = 48;
            int oy = p / 7, ox = p % 7;
            f32x4 acc = {0.f, 0.f, 0.f, 0.f};
#pragma unroll
            for (int ky = 0; ky < 3; ++ky)
#pragma unroll
                for (int kx = 0; kx < 3; ++kx) {
                    int pix = (oy + ky) * 9 + ox + kx;
#pragma unroll
                    for (int kc = 0; kc < 2; ++kc) {
                        short8 af = *(const short8*)&ob2[pix * 72 + kc * 32 + kq * 8];
                        acc = MFMA16(af, cfr[(ky * 3 + kx) * 2 + kc], acc);
                    }
                }
            int pm = mt * 16 + kq * 4;
#pragma unroll
            for (int r = 0; r < 4; ++r)
                ob3[(pm + r) * 64 + nt * 16 + lr] = f2bf(lrelu(acc[r] + bl3));
        }
    }
    __syncthreads();
    uint4* dst = (uint4*)(h3 + (size_t)n * 3136);
    for (int i = tid; i < 392; i += 512) dst[i] = ((uint4*)xs)[i];
}

// ========== bf16 GEMM, tile 128x64: C[M,N] = A[M,K] @ B[N,K]^T ==================
template <int OUT>
__global__ __launch_bounds__(256) void gemm_bf16(
    const short* __restrict__ A, const short* __restrict__ B,
    const float* __restrict__ bias, void* __restrict__ Cout,
    int M, int N, int K, int ldc,
    const float* __restrict__ reward = nullptr, const int* __restrict__ la = nullptr,
    const float* __restrict__ wih = nullptr, const float* __restrict__ bih = nullptr,
    const float* __restrict__ bhh = nullptr) {
    __shared__ short smem[15360];            // As[2][5120] | Bs[2][2560]
    int m0 = blockIdx.y * 128, n0 = blockIdx.x * 64;
    int tid = threadIdx.x;
    int lane = tid & 63, wid = tid >> 6;
    int wr = wid >> 1, wc = wid & 1;
    int lr = lane & 15, kq = lane >> 4;
    f32x4 acc[4][2];
#pragma unroll
    for (int i = 0; i < 4; ++i)
#pragma unroll
        for (int j = 0; j < 2; ++j) acc[i][j] = (f32x4){0.f, 0.f, 0.f, 0.f};

    int nsteps = K >> 5;
#define STAGE(k0, buf)                                                          \
    {                                                                           \
        short* As = smem + (buf) * 5120;                                        \
        short* Bs = smem + 10240 + (buf) * 2560;                                \
        for (int i = tid; i < 512; i += 256) {                                  \
            int row = i >> 2, c4 = i & 3;                                       \
            *(uint4*)&As[row * 40 + c4 * 8] =                                   \
                *(const uint4*)&A[(size_t)(m0 + row) * K + (k0) + c4 * 8];      \
        }                                                                       \
        {                                                                       \
            int row = tid >> 2, c4 = tid & 3;                                   \
            *(uint4*)&Bs[row * 40 + c4 * 8] =                                   \
                *(const uint4*)&B[(size_t)(n0 + row) * K + (k0) + c4 * 8];      \
        }                                                                       \
    }
    STAGE(0, 0);
    __syncthreads();
    for (int ks = 0; ks < nsteps; ++ks) {
        int buf = ks & 1;
        if (ks + 1 < nsteps) STAGE((ks + 1) * 32, buf ^ 1);
        short* As = smem + buf * 5120;
        short* Bs = smem + 10240 + buf * 2560;
        short8 af[4], bfr[2];
#pragma unroll
        for (int i = 0; i < 4; ++i)
            af[i] = *(const short8*)&As[(wr * 64 + i * 16 + lr) * 40 + kq * 8];
#pragma unroll
        for (int j = 0; j < 2; ++j)
            bfr[j] = *(const short8*)&Bs[(wc * 32 + j * 16 + lr) * 40 + kq * 8];
#pragma unroll
        for (int i = 0; i < 4; ++i)
#pragma unroll
            for (int j = 0; j < 2; ++j)
                acc[i][j] = MFMA16(af[i], bfr[j], acc[i][j]);
        __syncthreads();
    }
#undef STAGE
    if (OUT == 2) {
        float* C = (float*)Cout;
#pragma unroll
        for (int i = 0; i < 4; ++i)
#pragma unroll
            for (int j = 0; j < 2; ++j) {
                int col = n0 + wc * 32 + j * 16 + lr;
                const float* wrow = wih + (size_t)col * 529;
                float base = bih[col] + bhh[col];
                float w512 = wrow[512];
#pragma unroll
                for (int r = 0; r < 4; ++r) {
                    int row = m0 + wr * 64 + i * 16 + kq * 4 + r;
                    C[(size_t)row * ldc + col] =
                        acc[i][j][r] + base + reward[row] * w512 + wrow[513 + la[row]];
                }
            }
    } else {
        short* ob = smem;                             // 128x64 bf16 bounce
#pragma unroll
        for (int i = 0; i < 4; ++i)
#pragma unroll
            for (int j = 0; j < 2; ++j) {
                int col = wc * 32 + j * 16 + lr;
                float bl = bias[n0 + col];
#pragma unroll
                for (int r = 0; r < 4; ++r) {
                    int row = wr * 64 + i * 16 + kq * 4 + r;
                    ob[row * 64 + col] = f2bf(lrelu(acc[i][j][r] + bl));
                }
            }
        __syncthreads();
        short* C = (short*)Cout;
        for (int i = tid; i < 1024; i += 256) {
            int row = i >> 3, c8 = i & 7;
            *(uint4*)&C[(size_t)(m0 + row) * ldc + n0 + c8 * 8] =
                *(uint4*)&ob[row * 64 + c8 * 8];
        }
    }
}

// ---------- LSTM v13: BATCH-SPLIT, zero cross-WG sync ---------------------------
// 16 WGs, each owns 2 batches x ALL 256 units with the FULL 1024x256 bf16 Whh
// local: wave w (8 waves) covers gate rows w*128..+127 as 8 row-tiles of 16;
// tiles 0..5 resident in regs (48 short8 = 192 VGPR; 2 waves/SIMD -> 256 budget,
// R9-proven AGPR pattern), tiles 6..7 in LDS wL (128 KB, frag-layout,
// conflict-free ds_read_b128).  h(t) never leaves the CU: pointwise writes hB
// directly.  No flags, no hpub, no spin.  2 barriers/step.
__global__ __launch_bounds__(512, 2) void lstm_bs_k(
    const float* __restrict__ gx,        // [N_,1024]
    const float* __restrict__ whh,       // [1024,256] fp32
    const unsigned char* __restrict__ dones,
    const float* __restrict__ hx,        // [2,B_,256]
    float* __restrict__ hs) {            // [N_,256]
    const int tid = threadIdx.x;
    const int g2 = blockIdx.x;           // batches g2*2, g2*2+1
    const int lane = tid & 63, w = tid >> 6;     // 8 waves
    const int lr = lane & 15, kq = lane >> 4;

    __shared__ short wL[65536];          // 128 KB: tiles 6,7 of each wave, frag layout
    __shared__ short hB[16 * 264];       // 8.4 KB [col 16 (2 real)][k 256 +8 pad]
    __shared__ float gate_s[4 * 256 * 2];// 8 KB   [gate][unit][batch]

    // ---- resident A-frags: tiles mi 0..5, row = w*128 + mi*16 + lr ----
    short8 afr[6][8];
#pragma unroll
    for (int mi = 0; mi < 6; ++mi) {
        int row = w * 128 + mi * 16 + lr;
        const float* wrp = whh + (size_t)row * 256;
#pragma unroll
        for (int kt = 0; kt < 8; ++kt) {
            int k0 = kt * 32 + kq * 8;
            float4 a = *(const float4*)(wrp + k0);
            float4 b = *(const float4*)(wrp + k0 + 4);
            short8 f;
            f[0] = f2bf(a.x); f[1] = f2bf(a.y); f[2] = f2bf(a.z); f[3] = f2bf(a.w);
            f[4] = f2bf(b.x); f[5] = f2bf(b.y); f[6] = f2bf(b.z); f[7] = f2bf(b.w);
            afr[mi][kt] = f;
        }
    }
    {   // pin against rematerialization (R2/R3/R5/R10 lesson)
        int* ap = (int*)afr;
#pragma unroll
        for (int i = 0; i < 192; ++i) asm volatile("" : "+v"(ap[i]));
    }

    // ---- pack tiles 6,7 of every wave into wL (frag layout, once) ----
    // slot s: w2=s>>10, m2=(s>>9)&1, kt=(s>>6)&7, ln=s&63
    for (int s = tid; s < 8192; s += 512) {
        int w2 = s >> 10, m2 = (s >> 9) & 1, kt = (s >> 6) & 7, ln = s & 63;
        int row = w2 * 128 + (6 + m2) * 16 + (ln & 15);
        int k0 = kt * 32 + (ln >> 4) * 8;
        const float* wrp = whh + (size_t)row * 256 + k0;
        short8 f;
#pragma unroll
        for (int e = 0; e < 8; ++e) f[e] = f2bf(wrp[e]);
        *(short8*)&wL[s * 8] = f;
    }

    // zero hB cols 2..15 once
    for (int i = tid; i < 14 * 264; i += 512) hB[2 * 264 + i] = 0;

    const int u = tid >> 1, bt = tid & 1;        // pointwise ownership: unit,batch
    const int b = g2 * 2 + bt;
    float cc = hx[(size_t)B_ * LH_ + b * LH_ + u];

    // ---- t=1 staging from hx (512 threads, one value each) ----
    {
        int bt2 = tid >> 8, k = tid & 255;       // bt2 0..1
        int b2 = g2 * 2 + bt2;
        float hv = hx[b2 * LH_ + k];
        if (dones[b2]) hv = 0.f;
        hB[bt2 * 264 + k] = f2bf(hv);
    }
    __syncthreads();

    for (int t = 1; t <= T_; ++t) {
        const int nb0 = (t - 1) * B_;
        // ---- prefetch gx (independent of h; overlaps MFMA) ----
        float gxv[4];
#pragma unroll
        for (int gg2 = 0; gg2 < 4; ++gg2)
            gxv[gg2] = gx[(size_t)(nb0 + b) * 1024 + gg2 * 256 + u];

        // ---- MFMA: 128 gate rows x 2 batches per wave ----
        f32x4 acc[8];
#pragma unroll
        for (int mi = 0; mi < 8; ++mi) acc[mi] = (f32x4){0.f, 0.f, 0.f, 0.f};
#pragma unroll
        for (int kt = 0; kt < 8; ++kt) {
            short8 bfr = *(const short8*)&hB[lr * 264 + kt * 32 + kq * 8];
#pragma unroll
            for (int mi = 0; mi < 6; ++mi)
                acc[mi] = MFMA16(afr[mi][kt], bfr, acc[mi]);
#pragma unroll
            for (int m2 = 0; m2 < 2; ++m2) {
                short8 lA = *(const short8*)&wL[(((w * 2 + m2) * 8 + kt) * 64 + lane) * 8];
                acc[6 + m2] = MFMA16(lA, bfr, acc[6 + m2]);
            }
        }
        if (lr < 2) {                                // cols 0,1 = real batches
#pragma unroll
            for (int mi = 0; mi < 8; ++mi)
#pragma unroll
                for (int r = 0; r < 4; ++r) {
                    int row = w * 128 + mi * 16 + kq * 4 + r;
                    gate_s[(row >> 8) * 512 + (row & 255) * 2 + lr] = acc[mi][r];
                }
        }
        __syncthreads();                             // gates done; hB reads done

        // ---- pointwise: 256 units x 2 batches == 512 threads ----
        {
            bool dn = dones[nb0 + b] != 0;
            float gi = gate_s[0 * 512 + u * 2 + bt] + gxv[0];
            float gf = gate_s[1 * 512 + u * 2 + bt] + gxv[1];
            float gg = gate_s[2 * 512 + u * 2 + bt] + gxv[2];
            float go = gate_s[3 * 512 + u * 2 + bt] + gxv[3];
            float ccv = dn ? 0.f : cc;
            float si = 1.f / (1.f + expf(-gi));
            float sf = 1.f / (1.f + expf(-gf));
            float so = 1.f / (1.f + expf(-go));
            float c2 = sf * ccv + si * tanhf(gg);
            float h2 = so * tanhf(c2);
            cc = c2;
            if (t < T_) {                            // h(t) for next step, pre-masked
                hB[bt * 264 + u] = f2bf(dones[t * B_ + b] ? 0.f : h2);
            }
            hs[(size_t)(nb0 + b) * LH_ + u] = h2;
        }
        __syncthreads();                             // hB(t) ready for next MFMA
    }
}

// ---------- heads ----------
__global__ void head_k(const float* __restrict__ hs,
                       const float* __restrict__ aw, const float* __restrict__ ab,
                       const float* __restrict__ cw, const float* __restrict__ cb,
                       float* __restrict__ out) {
    int gid = blockIdx.x * 256 + threadIdx.x;       // N_*17
    if (gid >= N_ * 17) return;
    int n = gid / 17, r = gid % 17;
    const float* f = hs + (size_t)n * 256;
    if (r < 16) {
        const float* w = aw + r * 256;
        float acc = ab[r];
        for (int k = 0; k < 256; ++k) acc = fmaf(f[k], w[k], acc);
        if (isnan(acc)) acc = 1e-12f;
        out[(size_t)n * 16 + r] = acc;
    } else {
        float acc = cb[0];
        for (int k = 0; k < 256; ++k) acc = fmaf(f[k], cw[k], acc);
        out[(size_t)N_ * 16 + n] = acc;
    }
}

extern "C" void kernel_launch(void* const* d_in, const int* in_sizes, int n_in,
                              void* d_out, int out_size, void* d_ws, size_t ws_size,
                              hipStream_t stream) {
    const float* x      = (const float*)d_in[0];
    const int* la       = (const int*)d_in[1];
    const float* reward = (const float*)d_in[2];
    const unsigned char* dones = (const unsigned char*)d_in[3];
    const float* hx     = (const float*)d_in[4];
    const float* c1w = (const float*)d_in[5];  const float* c1b = (const float*)d_in[6];
    const float* c2w = (const float*)d_in[7];  const float* c2b = (const float*)d_in[8];
    const float* c3w = (const float*)d_in[9];  const float* c3b = (const float*)d_in[10];
    const float* fcw = (const float*)d_in[11]; const float* fcb = (const float*)d_in[12];
    const float* wih = (const float*)d_in[13]; const float* whh = (const float*)d_in[14];
    const float* bih = (const float*)d_in[15]; const float* bhh = (const float*)d_in[16];
    const float* aw  = (const float*)d_in[17]; const float* ab  = (const float*)d_in[18];
    const float* cw  = (const float*)d_in[19]; const float* cb  = (const float*)d_in[20];

    char* wsb = (char*)d_ws;
    short* h3   = (short*)(wsb + 92078080);              // 16,056,320 B
    short* hfc  = (short*)(wsb + 108134400);             //  2,621,440
    float* gx   = (float*)(wsb + 110755840);             // 10,485,760
    float* hs   = (float*)(wsb + 121241600);             //  2,621,440
    short* wp1  = (short*)(wsb + 123932672);             //     16,384
    short* wp2  = (short*)(wsb + 123949056);             //     65,536
    short* wp3  = (short*)(wsb + 124014592);             //     73,728
    short* wfcP = (short*)(wsb + 124088320);             //  3,211,264
    short* wihP = (short*)(wsb + 127299584);             //  1,048,576

    pack_all_k<<<2864, 256, 0, stream>>>(c1w, c2w, c3w, fcw, wih,
                                         wp1, wp2, wp3, wfcP, wihP);

    conv123_mfma<<<2560, 512, 0, stream>>>(x, wp1, c1b, wp2, c2b, wp3, c3b, h3);

    gemm_bf16<1><<<dim3(8, 20), 256, 0, stream>>>(h3, wfcP, fcb, hfc,
                                                  2560, 512, 3136, 512);
    gemm_bf16<2><<<dim3(16, 20), 256, 0, stream>>>(hfc, wihP, nullptr, gx,
                                                   2560, 1024, 512, 1024,
                                                   reward, la, wih, bih, bhh);

    lstm_bs_k<<<16, 512, 0, stream>>>(gx, whh, dones, hx, hs);
    head_k<<<170, 256, 0, stream>>>(hs, aw, ab, cw, cb, (float*)d_out);
}